// Round 6
// baseline (635.824 us; speedup 1.0000x reference)
//
#include <hip/hip_runtime.h>
#include <hip/hip_bf16.h>

typedef unsigned short u16;
typedef __attribute__((ext_vector_type(8))) short bf16x8;
typedef __attribute__((ext_vector_type(4))) float f32x4;
typedef __attribute__((ext_vector_type(8))) unsigned short u16x8;
typedef __attribute__((ext_vector_type(4))) unsigned short u16x4;

#define B_ 4
#define S_ 2048
#define E_ 1024
#define H_ 16
#define D_ 64
#define F_ 4096
#define M_ 8192   // B*S tokens

__device__ __forceinline__ float bf2f(u16 u) {
    union { unsigned int i; float f; } v; v.i = ((unsigned int)u) << 16; return v.f;
}
__device__ __forceinline__ u16 f2bf(float f) {
    union { float f; unsigned int i; } v; v.f = f;
    unsigned int r = v.i + 0x7FFFu + ((v.i >> 16) & 1u);
    return (u16)(r >> 16);
}
__device__ __forceinline__ u16 f2bfh(float f) {
    __hip_bfloat16 h = __float2bfloat16(f);
    return *reinterpret_cast<u16*>(&h);
}

// ---------------- cast x (f32 -> bf16), 8 elems/thread ----------------
__global__ __launch_bounds__(256) void cast_f32_bf16(const float* __restrict__ in,
                                                     u16* __restrict__ out) {
    const int i = blockIdx.x * 256 + threadIdx.x;
    const f32x4* p = (const f32x4*)in + (size_t)i * 2;
    f32x4 a = p[0], b = p[1];
    u16x8 o;
    o[0] = f2bf(a[0]); o[1] = f2bf(a[1]); o[2] = f2bf(a[2]); o[3] = f2bf(a[3]);
    o[4] = f2bf(b[0]); o[5] = f2bf(b[1]); o[6] = f2bf(b[2]); o[7] = f2bf(b[3]);
    *((u16x8*)out + i) = o;
}

// ---------------- transpose + cast: w[R][C] f32 -> wT[C][R] bf16 ----------------
__global__ __launch_bounds__(256) void transpose_cast(const float* __restrict__ w,
                                                      u16* __restrict__ wT,
                                                      int R, int C) {
    __shared__ float tile[32][33];
    const int tx = threadIdx.x & 31, ty = threadIdx.x >> 5;
    const int c0 = blockIdx.x * 32, r0 = blockIdx.y * 32;
#pragma unroll
    for (int i = 0; i < 4; ++i)
        tile[ty + i * 8][tx] = w[(size_t)(r0 + ty + i * 8) * C + c0 + tx];
    __syncthreads();
#pragma unroll
    for (int i = 0; i < 4; ++i)
        wT[(size_t)(c0 + ty + i * 8) * R + r0 + tx] = f2bf(tile[tx][ty + i * 8]);
}

// ---------------- concat q/k/v bias into [3072] f32 ----------------
__global__ __launch_bounds__(256) void concat_bias(const float* __restrict__ qb,
                                                   const float* __restrict__ kb,
                                                   const float* __restrict__ vb,
                                                   float* __restrict__ dst) {
    const int i = blockIdx.x * 256 + threadIdx.x;
    float v = (i < 1024) ? qb[i] : ((i < 2048) ? kb[i - 1024] : vb[i - 2048]);
    dst[i] = v;
}

// ---------------- K/V repack for attention ----------------
// kc[bh][s:2048][d:64]          (contiguous 128B rows -> coalesced LDS staging)
// vt[bh][kt:32][d:64][k:64]     (contiguous 8KB PV tiles -> coalesced V fragments)
__global__ __launch_bounds__(256) void transpose_kv(const u16* __restrict__ qkv,
                                                    u16* __restrict__ vt,
                                                    u16* __restrict__ kc) {
    __shared__ u16 t2[64 * 66];
    const int s0 = blockIdx.x * 64;
    const int bh = blockIdx.y;
    const int b = bh >> 4, h = bh & 15;
    const size_t ksec = ((size_t)b * S_) * 3072 + 1024 + (size_t)h * 64;
    const size_t vsec = ((size_t)b * S_) * 3072 + 2048 + (size_t)h * 64;
    const int t = threadIdx.x;
    const int sr = t >> 3, dc = (t & 7) * 8;
#pragma unroll
    for (int p = 0; p < 2; ++p) {
        const int s = sr + p * 32;
        // K copy (contiguous destination rows)
        u16x8 kv = *(const u16x8*)(qkv + ksec + (size_t)(s0 + s) * 3072 + dc);
        *(u16x8*)(kc + ((size_t)bh * S_ + s0 + s) * 64 + dc) = kv;
        // V -> LDS for transpose
        u16x8 v = *(const u16x8*)(qkv + vsec + (size_t)(s0 + s) * 3072 + dc);
#pragma unroll
        for (int e = 0; e < 8; ++e) t2[(dc + e) * 66 + s] = v[e];
    }
    __syncthreads();
    const int dr = t >> 3, sc2 = (t & 7) * 8;
#pragma unroll
    for (int p = 0; p < 2; ++p) {
        const int d = dr + p * 32;
        u16x8 o;
#pragma unroll
        for (int e = 0; e < 8; ++e) o[e] = t2[d * 66 + sc2 + e];
        *(u16x8*)(vt + (((size_t)bh * 32 + blockIdx.x) * 64 + d) * 64 + sc2) = o;
    }
}

// ---------------- bf16 GEMM: C[M,N] = A[M,K] * Bt[N,K]^T + bias (+relu) ----------------
// 128x128 tile, BK=64, 4 waves (2x2), 16x16x32 MFMA, global_load_lds staging.
__global__ __launch_bounds__(256) void gemm_bf16(const u16* __restrict__ A,
                                                 const u16* __restrict__ Bt,
                                                 const float* __restrict__ bias,
                                                 u16* __restrict__ C,
                                                 int N, int K, int relu) {
    __shared__ __align__(16) u16 As[128 * 64];
    __shared__ __align__(16) u16 Bs[128 * 64];
    const int tid = threadIdx.x;
    const int wid = tid >> 6, lane = tid & 63;
    const int mbase = blockIdx.y * 128, nbase = blockIdx.x * 128;
    const int wr = (wid >> 1) * 64, wc = (wid & 1) * 64;

    f32x4 acc[4][4];
    const f32x4 z = {0.f, 0.f, 0.f, 0.f};
#pragma unroll
    for (int m = 0; m < 4; ++m)
#pragma unroll
        for (int n = 0; n < 4; ++n) acc[m][n] = z;

    const int Lb = wid * 1024 + lane * 16;  // byte offset within 16KB tile
    const int kIters = K >> 6;

    for (int kb = 0; kb < kIters; ++kb) {
        __syncthreads();
#pragma unroll
        for (int c = 0; c < 4; ++c) {
            const int L = c * 4096 + Lb;
            const int row = L >> 7;        // 128 bytes per row (64 bf16)
            const int cbyte = L & 127;
            const u16* ga = A + (size_t)(mbase + row) * K + (kb << 6) + (cbyte >> 1);
            const u16* gb = Bt + (size_t)(nbase + row) * K + (kb << 6) + (cbyte >> 1);
            __builtin_amdgcn_global_load_lds(
                (const __attribute__((address_space(1))) void*)ga,
                (__attribute__((address_space(3))) void*)((char*)As + c * 4096 + wid * 1024),
                16, 0, 0);
            __builtin_amdgcn_global_load_lds(
                (const __attribute__((address_space(1))) void*)gb,
                (__attribute__((address_space(3))) void*)((char*)Bs + c * 4096 + wid * 1024),
                16, 0, 0);
        }
        __syncthreads();

        bf16x8 af[4][2], bfr[4][2];
#pragma unroll
        for (int m = 0; m < 4; ++m) {
            const int r = wr + m * 16 + (lane & 15);
            const char* base = (const char*)As + r * 128 + ((lane >> 4) * 16);
            af[m][0] = *(const bf16x8*)(base);
            af[m][1] = *(const bf16x8*)(base + 64);
        }
#pragma unroll
        for (int n = 0; n < 4; ++n) {
            const int r = wc + n * 16 + (lane & 15);
            const char* base = (const char*)Bs + r * 128 + ((lane >> 4) * 16);
            bfr[n][0] = *(const bf16x8*)(base);
            bfr[n][1] = *(const bf16x8*)(base + 64);
        }
#pragma unroll
        for (int m = 0; m < 4; ++m)
#pragma unroll
            for (int n = 0; n < 4; ++n) {
                acc[m][n] = __builtin_amdgcn_mfma_f32_16x16x32_bf16(af[m][0], bfr[n][0], acc[m][n], 0, 0, 0);
                acc[m][n] = __builtin_amdgcn_mfma_f32_16x16x32_bf16(af[m][1], bfr[n][1], acc[m][n], 0, 0, 0);
            }
    }

    // epilogue: C row = (lane>>4)*4 + reg, col = lane&15 (verified layout)
#pragma unroll
    for (int m = 0; m < 4; ++m) {
        const int rowb = mbase + wr + m * 16 + ((lane >> 4) * 4);
#pragma unroll
        for (int n = 0; n < 4; ++n) {
            const int col = nbase + wc + n * 16 + (lane & 15);
            const float bz = bias[col];
#pragma unroll
            for (int r = 0; r < 4; ++r) {
                float v = acc[m][n][r] + bz;
                if (relu) v = fmaxf(v, 0.f);
                C[(size_t)(rowb + r) * N + col] = f2bf(v);
            }
        }
    }
}

// ---------------- flash attention v5: coalesced K/V paths ----------------
// grid: (S/128, B*H); block 256 = 4 waves; each wave owns 32 q-rows.
// K from kc[bh][s][64] via double-buffered global_load_lds (pre-swizzled source,
//   XOR involution colb ^= (row&7)<<4 on source and LDS read — rule 21, R5-proven).
// V from tile-contiguous vt[bh][kt][64][64]: fragments 16 lines/inst.
// P: wave-private padded LDS. Softmax: exp2-domain, deferred row-sum reduce.
#define PSTRIDE 72
#define NT_ (S_ / 64)
__global__ __launch_bounds__(256) void attn_flash5(const u16* __restrict__ qkv,
                                                   const u16* __restrict__ kcg,
                                                   const u16* __restrict__ vtg,
                                                   u16* __restrict__ att) {
    __shared__ __align__(16) u16 Kt[2][64 * 64];       // 8KB per buffer, swizzled
    __shared__ __align__(16) u16 Ps[4][32 * PSTRIDE];  // per-wave P
    const int tid = threadIdx.x, wid = tid >> 6, lane = tid & 63;
    const int bh = blockIdx.y, b = bh >> 4, h = bh & 15;
    const size_t tok0 = (size_t)b * S_;
    const int lg = lane >> 4, lr = lane & 15;
    const int q0 = blockIdx.x * 128 + wid * 32;

    // Q fragments (held in regs for the whole kernel)
    bf16x8 qf[2][2];
#pragma unroll
    for (int qb = 0; qb < 2; ++qb) {
        const u16* qp = qkv + (tok0 + q0 + qb * 16 + lr) * 3072 + h * 64 + lg * 8;
        qf[qb][0] = *(const bf16x8*)qp;
        qf[qb][1] = *(const bf16x8*)(qp + 32);
    }

    // K staging source (pre-swizzled per lane; kc rows are 64 elems = 128B)
    const int srow = wid * 8 + (lane >> 3);              // rows 0..31 (chunk 1 adds 32; (row&7) unchanged)
    const int scolb = ((lane & 7) * 16) ^ ((srow & 7) << 4);
    const u16* kbase = kcg + (size_t)bh * S_ * 64;
    const u16* ksrc0 = kbase + (size_t)srow * 64 + (scolb >> 1);
    const u16* ksrc1 = kbase + (size_t)(srow + 32) * 64 + (scolb >> 1);

    const u16* vtb = vtg + (size_t)bh * 32 * 4096 + lg * 8;   // + kt*4096 + (nt*16+lr)*64
    u16* Pw = Ps[wid];

    f32x4 accv[2][4];
    const f32x4 z = {0.f, 0.f, 0.f, 0.f};
#pragma unroll
    for (int qb = 0; qb < 2; ++qb)
#pragma unroll
        for (int nt = 0; nt < 4; ++nt) accv[qb][nt] = z;
    float mrow[2][4], lrow[2][4];
#pragma unroll
    for (int qb = 0; qb < 2; ++qb)
#pragma unroll
        for (int r = 0; r < 4; ++r) { mrow[qb][r] = -1e30f; lrow[qb][r] = 0.f; }

    // prologue: stage tile 0 into buffer 0
    __builtin_amdgcn_global_load_lds(
        (const __attribute__((address_space(1))) void*)ksrc0,
        (__attribute__((address_space(3))) void*)((char*)Kt[0] + wid * 1024),
        16, 0, 0);
    __builtin_amdgcn_global_load_lds(
        (const __attribute__((address_space(1))) void*)ksrc1,
        (__attribute__((address_space(3))) void*)((char*)Kt[0] + 4096 + wid * 1024),
        16, 0, 0);
    __syncthreads();

    const float CSC = 0.125f * 1.44269504088896341f;   // log2(e)/8

    for (int kt = 0; kt < NT_; ++kt) {
        const int cur = kt & 1;
        // ---- stage next K tile (completes at this iter's barrier) ----
        if (kt + 1 < NT_) {
            const size_t adv = (size_t)(kt + 1) * 64 * 64;
            __builtin_amdgcn_global_load_lds(
                (const __attribute__((address_space(1))) void*)(ksrc0 + adv),
                (__attribute__((address_space(3))) void*)((char*)Kt[cur ^ 1] + wid * 1024),
                16, 0, 0);
            __builtin_amdgcn_global_load_lds(
                (const __attribute__((address_space(1))) void*)(ksrc1 + adv),
                (__attribute__((address_space(3))) void*)((char*)Kt[cur ^ 1] + 4096 + wid * 1024),
                16, 0, 0);
        }
        // ---- V fragments (tile-contiguous): issue early, consume after softmax ----
        bf16x8 vf[4][2];
#pragma unroll
        for (int nt = 0; nt < 4; ++nt) {
            const u16* vp = vtb + kt * 4096 + (nt * 16 + lr) * 64;
            vf[nt][0] = *(const bf16x8*)vp;
            vf[nt][1] = *(const bf16x8*)(vp + 32);
        }
        // ---- K fragments from LDS (swizzled read, 2-way conflicts only) ----
        bf16x8 kf[4][2];
#pragma unroll
        for (int kb = 0; kb < 4; ++kb) {
            const int row = kb * 16 + lr, sw = (row & 7) << 4;
            const char* rbase = (const char*)Kt[cur] + row * 128;
            kf[kb][0] = *(const bf16x8*)(rbase + ((lg * 16) ^ sw));
            kf[kb][1] = *(const bf16x8*)(rbase + ((64 + lg * 16) ^ sw));
        }
        // ---- QK^T ----
        f32x4 sc[2][4];
        __builtin_amdgcn_s_setprio(1);
#pragma unroll
        for (int kb = 0; kb < 4; ++kb)
#pragma unroll
            for (int qb = 0; qb < 2; ++qb) {
                sc[qb][kb] = __builtin_amdgcn_mfma_f32_16x16x32_bf16(qf[qb][0], kf[kb][0], z, 0, 0, 0);
                sc[qb][kb] = __builtin_amdgcn_mfma_f32_16x16x32_bf16(qf[qb][1], kf[kb][1], sc[qb][kb], 0, 0, 0);
            }
        __builtin_amdgcn_s_setprio(0);

        // ---- online softmax (exp2 domain; per-lane partial sums) ----
        float alpha[2][4];
#pragma unroll
        for (int qb = 0; qb < 2; ++qb)
#pragma unroll
            for (int r = 0; r < 4; ++r) {
                const float v0 = sc[qb][0][r], v1 = sc[qb][1][r];
                const float v2 = sc[qb][2][r], v3 = sc[qb][3][r];
                float mx = fmaxf(fmaxf(v0, v1), fmaxf(v2, v3));
#pragma unroll
                for (int off = 1; off < 16; off <<= 1) mx = fmaxf(mx, __shfl_xor(mx, off));
                const float mold = mrow[qb][r];
                const float mnew = fmaxf(mold, mx * CSC);
                const float al = exp2f(mold - mnew);
                alpha[qb][r] = al;
                mrow[qb][r] = mnew;
                const float p0 = exp2f(__builtin_fmaf(v0, CSC, -mnew));
                const float p1 = exp2f(__builtin_fmaf(v1, CSC, -mnew));
                const float p2 = exp2f(__builtin_fmaf(v2, CSC, -mnew));
                const float p3 = exp2f(__builtin_fmaf(v3, CSC, -mnew));
                lrow[qb][r] = al * lrow[qb][r] + ((p0 + p1) + (p2 + p3));
                const int rowP = qb * 16 + lg * 4 + r;
                u16* pw = Pw + rowP * PSTRIDE + lr;
                pw[0]  = f2bfh(p0);
                pw[16] = f2bfh(p1);
                pw[32] = f2bfh(p2);
                pw[48] = f2bfh(p3);
            }
        // rescale accumulator
#pragma unroll
        for (int qb = 0; qb < 2; ++qb)
#pragma unroll
            for (int nt = 0; nt < 4; ++nt) {
                f32x4 t = accv[qb][nt];
#pragma unroll
                for (int r = 0; r < 4; ++r) t[r] *= alpha[qb][r];
                accv[qb][nt] = t;
            }

        __syncthreads();   // fences: P stores (lgkm) + K stage (vmcnt) + buffer flip

        // ---- PV: A = P from LDS, B = V^T from regs ----
        bf16x8 pf[2][2];
#pragma unroll
        for (int qb = 0; qb < 2; ++qb) {
            const int rowP = qb * 16 + lr;
            pf[qb][0] = *(const bf16x8*)(Pw + rowP * PSTRIDE + lg * 8);
            pf[qb][1] = *(const bf16x8*)(Pw + rowP * PSTRIDE + 32 + lg * 8);
        }
        __builtin_amdgcn_s_setprio(1);
#pragma unroll
        for (int nt = 0; nt < 4; ++nt)
#pragma unroll
            for (int qb = 0; qb < 2; ++qb) {
                accv[qb][nt] = __builtin_amdgcn_mfma_f32_16x16x32_bf16(pf[qb][0], vf[nt][0], accv[qb][nt], 0, 0, 0);
                accv[qb][nt] = __builtin_amdgcn_mfma_f32_16x16x32_bf16(pf[qb][1], vf[nt][1], accv[qb][nt], 0, 0, 0);
            }
        __builtin_amdgcn_s_setprio(0);
    }

    // epilogue: final cross-lane row-sum reduce, then normalize and store
#pragma unroll
    for (int qb = 0; qb < 2; ++qb) {
        float inv[4];
#pragma unroll
        for (int r = 0; r < 4; ++r) {
            float s = lrow[qb][r];
#pragma unroll
            for (int off = 1; off < 16; off <<= 1) s += __shfl_xor(s, off);
            inv[r] = 1.0f / s;
        }
#pragma unroll
        for (int nt = 0; nt < 4; ++nt) {
            const int col = h * 64 + nt * 16 + lr;
#pragma unroll
            for (int r = 0; r < 4; ++r) {
                const size_t row = tok0 + q0 + qb * 16 + lg * 4 + r;
                att[row * E_ + col] = f2bf(accv[qb][nt][r] * inv[r]);
            }
        }
    }
}

// ---------------- fused residual + layernorm ----------------
__global__ __launch_bounds__(256) void ln_fused(const float* __restrict__ xr,
                                                const u16* __restrict__ yb,
                                                const float* __restrict__ g,
                                                const float* __restrict__ bb,
                                                float* __restrict__ ho,
                                                u16* __restrict__ hb) {
    const int wid = threadIdx.x >> 6, lane = threadIdx.x & 63;
    const int row = blockIdx.x * 4 + wid;
    const float* xp = xr + (size_t)row * E_;
    const u16* yp = yb + (size_t)row * E_;

    f32x4 t[4];
    float sum = 0.f, ss = 0.f;
#pragma unroll
    for (int j = 0; j < 4; ++j) {
        const int idx = j * 256 + lane * 4;
        const f32x4 xv = *(const f32x4*)(xp + idx);
        const u16x4 yv = *(const u16x4*)(yp + idx);
        f32x4 tv;
#pragma unroll
        for (int e = 0; e < 4; ++e) tv[e] = xv[e] + bf2f(yv[e]);
        t[j] = tv;
        sum += tv[0] + tv[1] + tv[2] + tv[3];
        ss += tv[0] * tv[0] + tv[1] * tv[1] + tv[2] * tv[2] + tv[3] * tv[3];
    }
#pragma unroll
    for (int off = 1; off < 64; off <<= 1) {
        sum += __shfl_xor(sum, off);
        ss += __shfl_xor(ss, off);
    }
    const float mu = sum * (1.f / 1024.f);
    const float var = ss * (1.f / 1024.f) - mu * mu;
    const float rstd = rsqrtf(var + 1e-5f);
#pragma unroll
    for (int j = 0; j < 4; ++j) {
        const int idx = j * 256 + lane * 4;
        const f32x4 gv = *(const f32x4*)(g + idx);
        const f32x4 bv = *(const f32x4*)(bb + idx);
        f32x4 ov;
#pragma unroll
        for (int e = 0; e < 4; ++e) ov[e] = (t[j][e] - mu) * rstd * gv[e] + bv[e];
        *(f32x4*)(ho + (size_t)row * E_ + idx) = ov;
        if (hb) {
            u16x4 o4;
#pragma unroll
            for (int e = 0; e < 4; ++e) o4[e] = f2bf(ov[e]);
            *(u16x4*)(hb + (size_t)row * E_ + idx) = o4;
        }
    }
}

// ---------------- launch ----------------
extern "C" void kernel_launch(void* const* d_in, const int* in_sizes, int n_in,
                              void* d_out, int out_size, void* d_ws, size_t ws_size,
                              hipStream_t stream) {
    const float* x    = (const float*)d_in[0];
    const float* qw   = (const float*)d_in[1];
    const float* qb   = (const float*)d_in[2];
    const float* kw   = (const float*)d_in[3];
    const float* kb   = (const float*)d_in[4];
    const float* vw   = (const float*)d_in[5];
    const float* vb   = (const float*)d_in[6];
    const float* ow   = (const float*)d_in[7];
    const float* ob   = (const float*)d_in[8];
    const float* ln1g = (const float*)d_in[9];
    const float* ln1b = (const float*)d_in[10];
    const float* w1   = (const float*)d_in[11];
    const float* b1   = (const float*)d_in[12];
    const float* w2   = (const float*)d_in[13];
    const float* b2   = (const float*)d_in[14];
    const float* ln2g = (const float*)d_in[15];
    const float* ln2b = (const float*)d_in[16];

    if (ws_size < 192950272ull) return;

    char* ws = (char*)d_ws;
    u16*  wqkvT = (u16*)(ws + 0);                // [3072][1024] bf16
    u16*  woT   = (u16*)(ws + 6291456);          // [1024][1024]
    u16*  w1T   = (u16*)(ws + 8388608);          // [4096][1024]
    u16*  w2T   = (u16*)(ws + 16777216);         // [1024][4096]
    float* bqkv = (float*)(ws + 25165824);       // [3072]
    u16*  xb    = (u16*)(ws + 25178112);         // [8192][1024]  (then reused as att)
    u16*  attb  = xb;
    u16*  qkvb  = (u16*)(ws + 41955328);         // [8192][3072]  (then ao)
    u16*  aob   = qkvb;
    u16*  vtg   = (u16*)(ws + 58732544);         // [64][32][64][64] bf16 (dead before hbb)
    u16*  hbb   = (u16*)(ws + 58732544);         // reused after attention completes
    u16*  ff2b  = (u16*)(ws + 75509760);
    float* hf   = (float*)(ws + 92286976);       // [8192][1024] f32
    u16*  ff1b  = (u16*)(ws + 125841408);        // [8192][4096]
    u16*  kcg   = (u16*)(ws + 125841408);        // [64][2048][64] bf16 (dead before ff1b)

    cast_f32_bf16<<<dim3(4096), dim3(256), 0, stream>>>(x, xb);
    transpose_cast<<<dim3(32, 32), dim3(256), 0, stream>>>(qw, wqkvT, 1024, 1024);
    transpose_cast<<<dim3(32, 32), dim3(256), 0, stream>>>(kw, wqkvT + 1024 * 1024, 1024, 1024);
    transpose_cast<<<dim3(32, 32), dim3(256), 0, stream>>>(vw, wqkvT + 2048 * 1024, 1024, 1024);
    transpose_cast<<<dim3(32, 32), dim3(256), 0, stream>>>(ow, woT, 1024, 1024);
    transpose_cast<<<dim3(128, 32), dim3(256), 0, stream>>>(w1, w1T, 1024, 4096);
    transpose_cast<<<dim3(32, 128), dim3(256), 0, stream>>>(w2, w2T, 4096, 1024);
    concat_bias<<<dim3(12), dim3(256), 0, stream>>>(qb, kb, vb, bqkv);

    // QKV: [8192,1024] x [1024,3072]
    gemm_bf16<<<dim3(24, 64), dim3(256), 0, stream>>>(xb, wqkvT, bqkv, qkvb, 3072, 1024, 0);
    // K/V repack for coalesced attention access
    transpose_kv<<<dim3(32, 64), dim3(256), 0, stream>>>(qkvb, vtg, kcg);
    // attention
    attn_flash5<<<dim3(16, 64), dim3(256), 0, stream>>>(qkvb, kcg, vtg, attb);
    // O-proj
    gemm_bf16<<<dim3(8, 64), dim3(256), 0, stream>>>(attb, woT, ob, aob, 1024, 1024, 0);
    // residual + LN1
    ln_fused<<<dim3(2048), dim3(256), 0, stream>>>(x, aob, ln1g, ln1b, hf, hbb);
    // FFN
    gemm_bf16<<<dim3(32, 64), dim3(256), 0, stream>>>(hbb, w1T, b1, ff1b, 4096, 1024, 1);
    gemm_bf16<<<dim3(8, 64), dim3(256), 0, stream>>>(ff1b, w2T, b2, ff2b, 1024, 4096, 0);
    // residual + LN2 -> output (f32)
    ln_fused<<<dim3(2048), dim3(256), 0, stream>>>(hf, ff2b, ln2g, ln2b, (float*)d_out, (u16*)nullptr);
}

// Round 7
// 507.547 us; speedup vs baseline: 1.2527x; 1.2527x over previous
//
#include <hip/hip_runtime.h>
#include <hip/hip_bf16.h>

typedef unsigned short u16;
typedef unsigned int u32;
typedef __attribute__((ext_vector_type(8))) short bf16x8;
typedef __attribute__((ext_vector_type(4))) float f32x4;
typedef __attribute__((ext_vector_type(16))) float f32x16;
typedef __attribute__((ext_vector_type(8))) unsigned short u16x8;
typedef __attribute__((ext_vector_type(4))) unsigned short u16x4;

#define B_ 4
#define S_ 2048
#define E_ 1024
#define H_ 16
#define D_ 64
#define F_ 4096
#define M_ 8192   // B*S tokens

__device__ __forceinline__ float bf2f(u16 u) {
    union { unsigned int i; float f; } v; v.i = ((unsigned int)u) << 16; return v.f;
}
__device__ __forceinline__ u16 f2bf(float f) {
    union { float f; unsigned int i; } v; v.f = f;
    unsigned int r = v.i + 0x7FFFu + ((v.i >> 16) & 1u);
    return (u16)(r >> 16);
}

// ---------------- cast x (f32 -> bf16), 8 elems/thread ----------------
__global__ __launch_bounds__(256) void cast_f32_bf16(const float* __restrict__ in,
                                                     u16* __restrict__ out) {
    const int i = blockIdx.x * 256 + threadIdx.x;
    const f32x4* p = (const f32x4*)in + (size_t)i * 2;
    f32x4 a = p[0], b = p[1];
    u16x8 o;
    o[0] = f2bf(a[0]); o[1] = f2bf(a[1]); o[2] = f2bf(a[2]); o[3] = f2bf(a[3]);
    o[4] = f2bf(b[0]); o[5] = f2bf(b[1]); o[6] = f2bf(b[2]); o[7] = f2bf(b[3]);
    *((u16x8*)out + i) = o;
}

// ---------------- transpose + cast: w[R][C] f32 -> wT[C][R] bf16 ----------------
__global__ __launch_bounds__(256) void transpose_cast(const float* __restrict__ w,
                                                      u16* __restrict__ wT,
                                                      int R, int C) {
    __shared__ float tile[32][33];
    const int tx = threadIdx.x & 31, ty = threadIdx.x >> 5;
    const int c0 = blockIdx.x * 32, r0 = blockIdx.y * 32;
#pragma unroll
    for (int i = 0; i < 4; ++i)
        tile[ty + i * 8][tx] = w[(size_t)(r0 + ty + i * 8) * C + c0 + tx];
    __syncthreads();
#pragma unroll
    for (int i = 0; i < 4; ++i)
        wT[(size_t)(c0 + ty + i * 8) * R + r0 + tx] = f2bf(tile[tx][ty + i * 8]);
}

// ---------------- concat q/k/v bias into [3072] f32 ----------------
__global__ __launch_bounds__(256) void concat_bias(const float* __restrict__ qb,
                                                   const float* __restrict__ kb,
                                                   const float* __restrict__ vb,
                                                   float* __restrict__ dst) {
    const int i = blockIdx.x * 256 + threadIdx.x;
    float v = (i < 1024) ? qb[i] : ((i < 2048) ? kb[i - 1024] : vb[i - 2048]);
    dst[i] = v;
}

// ---------------- K/V repack for attention ----------------
// kc[bh][s:2048][d:64]          (contiguous 128B rows -> coalesced LDS staging)
// vt[bh][kt:32][d:64][k:64]     (contiguous 8KB V^T tiles -> coalesced staging)
__global__ __launch_bounds__(256) void transpose_kv(const u16* __restrict__ qkv,
                                                    u16* __restrict__ vt,
                                                    u16* __restrict__ kc) {
    __shared__ u16 t2[64 * 66];
    const int s0 = blockIdx.x * 64;
    const int bh = blockIdx.y;
    const int b = bh >> 4, h = bh & 15;
    const size_t ksec = ((size_t)b * S_) * 3072 + 1024 + (size_t)h * 64;
    const size_t vsec = ((size_t)b * S_) * 3072 + 2048 + (size_t)h * 64;
    const int t = threadIdx.x;
    const int sr = t >> 3, dc = (t & 7) * 8;
#pragma unroll
    for (int p = 0; p < 2; ++p) {
        const int s = sr + p * 32;
        u16x8 kv = *(const u16x8*)(qkv + ksec + (size_t)(s0 + s) * 3072 + dc);
        *(u16x8*)(kc + ((size_t)bh * S_ + s0 + s) * 64 + dc) = kv;
        u16x8 v = *(const u16x8*)(qkv + vsec + (size_t)(s0 + s) * 3072 + dc);
#pragma unroll
        for (int e = 0; e < 8; ++e) t2[(dc + e) * 66 + s] = v[e];
    }
    __syncthreads();
    const int dr = t >> 3, sc2 = (t & 7) * 8;
#pragma unroll
    for (int p = 0; p < 2; ++p) {
        const int d = dr + p * 32;
        u16x8 o;
#pragma unroll
        for (int e = 0; e < 8; ++e) o[e] = t2[d * 66 + sc2 + e];
        *(u16x8*)(vt + (((size_t)bh * 32 + blockIdx.x) * 64 + d) * 64 + sc2) = o;
    }
}

// ---------------- bf16 GEMM: C[M,N] = A[M,K] * Bt[N,K]^T + bias (+relu) ----------------
__global__ __launch_bounds__(256) void gemm_bf16(const u16* __restrict__ A,
                                                 const u16* __restrict__ Bt,
                                                 const float* __restrict__ bias,
                                                 u16* __restrict__ C,
                                                 int N, int K, int relu) {
    __shared__ __align__(16) u16 As[128 * 64];
    __shared__ __align__(16) u16 Bs[128 * 64];
    const int tid = threadIdx.x;
    const int wid = tid >> 6, lane = tid & 63;
    const int mbase = blockIdx.y * 128, nbase = blockIdx.x * 128;
    const int wr = (wid >> 1) * 64, wc = (wid & 1) * 64;

    f32x4 acc[4][4];
    const f32x4 z = {0.f, 0.f, 0.f, 0.f};
#pragma unroll
    for (int m = 0; m < 4; ++m)
#pragma unroll
        for (int n = 0; n < 4; ++n) acc[m][n] = z;

    const int Lb = wid * 1024 + lane * 16;
    const int kIters = K >> 6;

    for (int kb = 0; kb < kIters; ++kb) {
        __syncthreads();
#pragma unroll
        for (int c = 0; c < 4; ++c) {
            const int L = c * 4096 + Lb;
            const int row = L >> 7;
            const int cbyte = L & 127;
            const u16* ga = A + (size_t)(mbase + row) * K + (kb << 6) + (cbyte >> 1);
            const u16* gb = Bt + (size_t)(nbase + row) * K + (kb << 6) + (cbyte >> 1);
            __builtin_amdgcn_global_load_lds(
                (const __attribute__((address_space(1))) void*)ga,
                (__attribute__((address_space(3))) void*)((char*)As + c * 4096 + wid * 1024),
                16, 0, 0);
            __builtin_amdgcn_global_load_lds(
                (const __attribute__((address_space(1))) void*)gb,
                (__attribute__((address_space(3))) void*)((char*)Bs + c * 4096 + wid * 1024),
                16, 0, 0);
        }
        __syncthreads();

        bf16x8 af[4][2], bfr[4][2];
#pragma unroll
        for (int m = 0; m < 4; ++m) {
            const int r = wr + m * 16 + (lane & 15);
            const char* base = (const char*)As + r * 128 + ((lane >> 4) * 16);
            af[m][0] = *(const bf16x8*)(base);
            af[m][1] = *(const bf16x8*)(base + 64);
        }
#pragma unroll
        for (int n = 0; n < 4; ++n) {
            const int r = wc + n * 16 + (lane & 15);
            const char* base = (const char*)Bs + r * 128 + ((lane >> 4) * 16);
            bfr[n][0] = *(const bf16x8*)(base);
            bfr[n][1] = *(const bf16x8*)(base + 64);
        }
#pragma unroll
        for (int m = 0; m < 4; ++m)
#pragma unroll
            for (int n = 0; n < 4; ++n) {
                acc[m][n] = __builtin_amdgcn_mfma_f32_16x16x32_bf16(af[m][0], bfr[n][0], acc[m][n], 0, 0, 0);
                acc[m][n] = __builtin_amdgcn_mfma_f32_16x16x32_bf16(af[m][1], bfr[n][1], acc[m][n], 0, 0, 0);
            }
    }

#pragma unroll
    for (int m = 0; m < 4; ++m) {
        const int rowb = mbase + wr + m * 16 + ((lane >> 4) * 4);
#pragma unroll
        for (int n = 0; n < 4; ++n) {
            const int col = nbase + wc + n * 16 + (lane & 15);
            const float bz = bias[col];
#pragma unroll
            for (int r = 0; r < 4; ++r) {
                float v = acc[m][n][r] + bz;
                if (relu) v = fmaxf(v, 0.f);
                C[(size_t)(rowb + r) * N + col] = f2bf(v);
            }
        }
    }
}

// ---------------- flash attention v6: swapped QK^T, in-register softmax ----------
// grid: (S/128, B*H); block 256 = 4 waves; each wave owns 32 q-rows.
// QK^T = mfma_32x32x16(K, Q): D[key][qrow], col=lane&31=qrow, row=crow(r,hi)=key
//   (crow(r,hi) = (r&3) + 8*(r>>2) + 4*hi  — m74/m101-verified C/D layout).
// P stays in registers: v_cvt_pk_bf16_f32 + v_permlane32_swap_b32 assemble
//   the PV A-fragments directly (m214-verified recipe).
// K and V^T double-buffered in LDS via pre-swizzled global_load_lds (rule 21).
// defer-max (T13, THR=8): acco rescale (16 ds_bpermute broadcast) only on max growth.
__device__ __forceinline__ u32 cvtpk_bf16(float lo, float hi2) {
    u32 r;
    asm("v_cvt_pk_bf16_f32 %0, %1, %2" : "=v"(r) : "v"(lo), "v"(hi2));
    return r;
}
__global__ __launch_bounds__(256) void attn_flash6(const u16* __restrict__ qkv,
                                                   const u16* __restrict__ kcg,
                                                   const u16* __restrict__ vtg,
                                                   u16* __restrict__ att) {
    __shared__ __align__(16) u16 Kt[2][64 * 64];   // 8KB each, swizzled
    __shared__ __align__(16) u16 Vt[2][64 * 64];   // V^T tiles, swizzled
    const int tid = threadIdx.x, wid = tid >> 6;
    const int lane = tid & 63, l31 = lane & 31, hi = lane >> 5;
    const int bh = blockIdx.y, b = bh >> 4, h = bh & 15;
    const size_t tok0 = (size_t)b * S_;
    const int q0 = blockIdx.x * 128 + wid * 32;

    // Q fragments: qf[dc] = Q[q0+l31][dc*16 + hi*8 .. +7]  (B-operand of swapped QK)
    bf16x8 qf[4];
    {
        const u16* qp = qkv + (tok0 + q0 + l31) * 3072 + h * 64 + hi * 8;
#pragma unroll
        for (int dc = 0; dc < 4; ++dc) qf[dc] = *(const bf16x8*)(qp + dc * 16);
    }

    // staging source (pre-swizzled involution colb ^= (row&7)<<4; linear LDS dest)
    const int srow = tid >> 3;                       // 0..31
    const int scolb = ((tid & 7) * 16) ^ ((srow & 7) << 4);
    const u16* kbase = kcg + ((size_t)bh * S_ + srow) * 64 + (scolb >> 1);
    const u16* vbase = vtg + (size_t)bh * 32 * 4096 + srow * 64 + (scolb >> 1);
    const int ldst = tid * 16;                       // byte offset in 8KB half-pair

    f32x16 acco0, acco1;
#pragma unroll
    for (int r = 0; r < 16; ++r) { acco0[r] = 0.f; acco1[r] = 0.f; }
    float m_reg = -1e30f, l_run = 0.f;

    // prologue: stage tile 0 into buffer 0
    __builtin_amdgcn_global_load_lds((const __attribute__((address_space(1))) void*)kbase,
        (__attribute__((address_space(3))) void*)((char*)Kt[0] + ldst), 16, 0, 0);
    __builtin_amdgcn_global_load_lds((const __attribute__((address_space(1))) void*)(kbase + 32 * 64),
        (__attribute__((address_space(3))) void*)((char*)Kt[0] + 4096 + ldst), 16, 0, 0);
    __builtin_amdgcn_global_load_lds((const __attribute__((address_space(1))) void*)vbase,
        (__attribute__((address_space(3))) void*)((char*)Vt[0] + ldst), 16, 0, 0);
    __builtin_amdgcn_global_load_lds((const __attribute__((address_space(1))) void*)(vbase + 32 * 64),
        (__attribute__((address_space(3))) void*)((char*)Vt[0] + 4096 + ldst), 16, 0, 0);
    __syncthreads();

    const float CSC = 0.125f * 1.44269504088896341f;   // log2(e)/8
    const int hb4 = hi * 16;                            // bpermute addr offset

    for (int kt = 0; kt < 32; ++kt) {
        const int cur = kt & 1;
        // ---- stage next tile (drained by end-of-iter barrier) ----
        if (kt + 1 < 32) {
            const size_t adv = (size_t)(kt + 1) * 4096;
            __builtin_amdgcn_global_load_lds((const __attribute__((address_space(1))) void*)(kbase + adv),
                (__attribute__((address_space(3))) void*)((char*)Kt[cur ^ 1] + ldst), 16, 0, 0);
            __builtin_amdgcn_global_load_lds((const __attribute__((address_space(1))) void*)(kbase + adv + 32 * 64),
                (__attribute__((address_space(3))) void*)((char*)Kt[cur ^ 1] + 4096 + ldst), 16, 0, 0);
            __builtin_amdgcn_global_load_lds((const __attribute__((address_space(1))) void*)(vbase + adv),
                (__attribute__((address_space(3))) void*)((char*)Vt[cur ^ 1] + ldst), 16, 0, 0);
            __builtin_amdgcn_global_load_lds((const __attribute__((address_space(1))) void*)(vbase + adv + 32 * 64),
                (__attribute__((address_space(3))) void*)((char*)Vt[cur ^ 1] + 4096 + ldst), 16, 0, 0);
        }

        // ---- swapped QK^T: p[key][qrow], lane&31 = qrow ----
        f32x16 p0, p1;
#pragma unroll
        for (int r = 0; r < 16; ++r) { p0[r] = 0.f; p1[r] = 0.f; }
        __builtin_amdgcn_s_setprio(1);
#pragma unroll
        for (int dc = 0; dc < 4; ++dc) {
            const int row0 = l31, row1 = 32 + l31;
            const bf16x8 kf0 = *(const bf16x8*)((const char*)Kt[cur] + row0 * 128 + ((dc * 32 + hi * 16) ^ ((row0 & 7) << 4)));
            const bf16x8 kf1 = *(const bf16x8*)((const char*)Kt[cur] + row1 * 128 + ((dc * 32 + hi * 16) ^ ((row1 & 7) << 4)));
            p0 = __builtin_amdgcn_mfma_f32_32x32x16_bf16(kf0, qf[dc], p0, 0, 0, 0);
            p1 = __builtin_amdgcn_mfma_f32_32x32x16_bf16(kf1, qf[dc], p1, 0, 0, 0);
        }
        __builtin_amdgcn_s_setprio(0);

        // ---- in-register row max (31 fmax) + lane-pair combine (1 permlane swap) ----
        float mx = p0[0];
#pragma unroll
        for (int r = 1; r < 16; ++r) mx = fmaxf(mx, p0[r]);
#pragma unroll
        for (int r = 0; r < 16; ++r) mx = fmaxf(mx, p1[r]);
        float sa = mx, sb = mx;
        asm volatile("v_permlane32_swap_b32 %0, %1" : "+v"(sa), "+v"(sb));
        const float fullm = fmaxf(sa, sb) * CSC;

        // ---- defer-max: rescale only when the running max actually grows ----
        if (!__all(fullm - m_reg <= 8.0f)) {
            const float mnew = fmaxf(m_reg, fullm);
            const float alf = exp2f(m_reg - mnew);
            l_run *= alf;
            m_reg = mnew;
            const int au = __float_as_int(alf);
#pragma unroll
            for (int r = 0; r < 16; ++r) {
                const int addr = ((r & 3) + 8 * (r >> 2)) * 4 + hb4;
                const float ar = __int_as_float(__builtin_amdgcn_ds_bpermute(addr, au));
                acco0[r] *= ar;
                acco1[r] *= ar;
            }
        }

        // ---- exp2 + partial row-sum (deferred cross-lane reduce) ----
        float pe0[16], pe1[16];
        float ls = 0.f;
#pragma unroll
        for (int r = 0; r < 16; ++r) {
            pe0[r] = exp2f(__builtin_fmaf(p0[r], CSC, -m_reg));
            pe1[r] = exp2f(__builtin_fmaf(p1[r], CSC, -m_reg));
            ls += pe0[r] + pe1[r];
        }
        l_run += ls;

        // ---- P -> PV A-fragments in registers (cvt_pk + permlane32_swap) ----
        union { u32 u[4]; bf16x8 v; } pa0, pa1, pa2, pa3;
        {
            u32 a, bswap, c, d;
            a = cvtpk_bf16(pe0[0], pe0[1]);  bswap = cvtpk_bf16(pe0[4], pe0[5]);
            asm volatile("v_permlane32_swap_b32 %0, %1" : "+v"(a), "+v"(bswap));
            c = cvtpk_bf16(pe0[2], pe0[3]);  d = cvtpk_bf16(pe0[6], pe0[7]);
            asm volatile("v_permlane32_swap_b32 %0, %1" : "+v"(c), "+v"(d));
            pa0.u[0] = a; pa0.u[1] = c; pa0.u[2] = bswap; pa0.u[3] = d;
            a = cvtpk_bf16(pe0[8], pe0[9]);  bswap = cvtpk_bf16(pe0[12], pe0[13]);
            asm volatile("v_permlane32_swap_b32 %0, %1" : "+v"(a), "+v"(bswap));
            c = cvtpk_bf16(pe0[10], pe0[11]); d = cvtpk_bf16(pe0[14], pe0[15]);
            asm volatile("v_permlane32_swap_b32 %0, %1" : "+v"(c), "+v"(d));
            pa1.u[0] = a; pa1.u[1] = c; pa1.u[2] = bswap; pa1.u[3] = d;
            a = cvtpk_bf16(pe1[0], pe1[1]);  bswap = cvtpk_bf16(pe1[4], pe1[5]);
            asm volatile("v_permlane32_swap_b32 %0, %1" : "+v"(a), "+v"(bswap));
            c = cvtpk_bf16(pe1[2], pe1[3]);  d = cvtpk_bf16(pe1[6], pe1[7]);
            asm volatile("v_permlane32_swap_b32 %0, %1" : "+v"(c), "+v"(d));
            pa2.u[0] = a; pa2.u[1] = c; pa2.u[2] = bswap; pa2.u[3] = d;
            a = cvtpk_bf16(pe1[8], pe1[9]);  bswap = cvtpk_bf16(pe1[12], pe1[13]);
            asm volatile("v_permlane32_swap_b32 %0, %1" : "+v"(a), "+v"(bswap));
            c = cvtpk_bf16(pe1[10], pe1[11]); d = cvtpk_bf16(pe1[14], pe1[15]);
            asm volatile("v_permlane32_swap_b32 %0, %1" : "+v"(c), "+v"(d));
            pa3.u[0] = a; pa3.u[1] = c; pa3.u[2] = bswap; pa3.u[3] = d;
        }

        // ---- PV: A = pa[ks] (P), B = V^T fragments from LDS ----
        __builtin_amdgcn_s_setprio(1);
#pragma unroll
        for (int dblk = 0; dblk < 2; ++dblk) {
            const int row = dblk * 32 + l31;
            const int sw = (row & 7) << 4;
            const char* vrow = (const char*)Vt[cur] + row * 128;
            const bf16x8 v0 = *(const bf16x8*)(vrow + ((0 * 32 + hi * 16) ^ sw));
            const bf16x8 v1 = *(const bf16x8*)(vrow + ((1 * 32 + hi * 16) ^ sw));
            const bf16x8 v2 = *(const bf16x8*)(vrow + ((2 * 32 + hi * 16) ^ sw));
            const bf16x8 v3 = *(const bf16x8*)(vrow + ((3 * 32 + hi * 16) ^ sw));
            if (dblk == 0) {
                acco0 = __builtin_amdgcn_mfma_f32_32x32x16_bf16(pa0.v, v0, acco0, 0, 0, 0);
                acco0 = __builtin_amdgcn_mfma_f32_32x32x16_bf16(pa1.v, v1, acco0, 0, 0, 0);
                acco0 = __builtin_amdgcn_mfma_f32_32x32x16_bf16(pa2.v, v2, acco0, 0, 0, 0);
                acco0 = __builtin_amdgcn_mfma_f32_32x32x16_bf16(pa3.v, v3, acco0, 0, 0, 0);
            } else {
                acco1 = __builtin_amdgcn_mfma_f32_32x32x16_bf16(pa0.v, v0, acco1, 0, 0, 0);
                acco1 = __builtin_amdgcn_mfma_f32_32x32x16_bf16(pa1.v, v1, acco1, 0, 0, 0);
                acco1 = __builtin_amdgcn_mfma_f32_32x32x16_bf16(pa2.v, v2, acco1, 0, 0, 0);
                acco1 = __builtin_amdgcn_mfma_f32_32x32x16_bf16(pa3.v, v3, acco1, 0, 0, 0);
            }
        }
        __builtin_amdgcn_s_setprio(0);

        __syncthreads();   // all reads of buf[cur] done; staged buf[cur^1] drained
    }

    // ---- epilogue: combine lane-pair l, broadcast 1/l per output row, store ----
    float la = l_run, lb = l_run;
    asm volatile("v_permlane32_swap_b32 %0, %1" : "+v"(la), "+v"(lb));
    const float linv = 1.0f / (la + lb);
    const int li = __float_as_int(linv);
#pragma unroll
    for (int r = 0; r < 16; ++r) {
        const int addr = ((r & 3) + 8 * (r >> 2)) * 4 + hb4;
        const float lr = __int_as_float(__builtin_amdgcn_ds_bpermute(addr, li));
        const int qrow = (r & 3) + 8 * (r >> 2) + 4 * hi;
        u16* orow = att + (tok0 + q0 + qrow) * E_ + h * 64 + l31;
        orow[0]  = f2bf(acco0[r] * lr);
        orow[32] = f2bf(acco1[r] * lr);
    }
}

// ---------------- fused residual + layernorm ----------------
__global__ __launch_bounds__(256) void ln_fused(const float* __restrict__ xr,
                                                const u16* __restrict__ yb,
                                                const float* __restrict__ g,
                                                const float* __restrict__ bb,
                                                float* __restrict__ ho,
                                                u16* __restrict__ hb) {
    const int wid = threadIdx.x >> 6, lane = threadIdx.x & 63;
    const int row = blockIdx.x * 4 + wid;
    const float* xp = xr + (size_t)row * E_;
    const u16* yp = yb + (size_t)row * E_;

    f32x4 t[4];
    float sum = 0.f, ss = 0.f;
#pragma unroll
    for (int j = 0; j < 4; ++j) {
        const int idx = j * 256 + lane * 4;
        const f32x4 xv = *(const f32x4*)(xp + idx);
        const u16x4 yv = *(const u16x4*)(yp + idx);
        f32x4 tv;
#pragma unroll
        for (int e = 0; e < 4; ++e) tv[e] = xv[e] + bf2f(yv[e]);
        t[j] = tv;
        sum += tv[0] + tv[1] + tv[2] + tv[3];
        ss += tv[0] * tv[0] + tv[1] * tv[1] + tv[2] * tv[2] + tv[3] * tv[3];
    }
#pragma unroll
    for (int off = 1; off < 64; off <<= 1) {
        sum += __shfl_xor(sum, off);
        ss += __shfl_xor(ss, off);
    }
    const float mu = sum * (1.f / 1024.f);
    const float var = ss * (1.f / 1024.f) - mu * mu;
    const float rstd = rsqrtf(var + 1e-5f);
#pragma unroll
    for (int j = 0; j < 4; ++j) {
        const int idx = j * 256 + lane * 4;
        const f32x4 gv = *(const f32x4*)(g + idx);
        const f32x4 bv = *(const f32x4*)(bb + idx);
        f32x4 ov;
#pragma unroll
        for (int e = 0; e < 4; ++e) ov[e] = (t[j][e] - mu) * rstd * gv[e] + bv[e];
        *(f32x4*)(ho + (size_t)row * E_ + idx) = ov;
        if (hb) {
            u16x4 o4;
#pragma unroll
            for (int e = 0; e < 4; ++e) o4[e] = f2bf(ov[e]);
            *(u16x4*)(hb + (size_t)row * E_ + idx) = o4;
        }
    }
}

// ---------------- launch ----------------
extern "C" void kernel_launch(void* const* d_in, const int* in_sizes, int n_in,
                              void* d_out, int out_size, void* d_ws, size_t ws_size,
                              hipStream_t stream) {
    const float* x    = (const float*)d_in[0];
    const float* qw   = (const float*)d_in[1];
    const float* qb   = (const float*)d_in[2];
    const float* kw   = (const float*)d_in[3];
    const float* kb   = (const float*)d_in[4];
    const float* vw   = (const float*)d_in[5];
    const float* vb   = (const float*)d_in[6];
    const float* ow   = (const float*)d_in[7];
    const float* ob   = (const float*)d_in[8];
    const float* ln1g = (const float*)d_in[9];
    const float* ln1b = (const float*)d_in[10];
    const float* w1   = (const float*)d_in[11];
    const float* b1   = (const float*)d_in[12];
    const float* w2   = (const float*)d_in[13];
    const float* b2   = (const float*)d_in[14];
    const float* ln2g = (const float*)d_in[15];
    const float* ln2b = (const float*)d_in[16];

    if (ws_size < 192950272ull) return;

    char* ws = (char*)d_ws;
    u16*  wqkvT = (u16*)(ws + 0);                // [3072][1024] bf16
    u16*  woT   = (u16*)(ws + 6291456);          // [1024][1024]
    u16*  w1T   = (u16*)(ws + 8388608);          // [4096][1024]
    u16*  w2T   = (u16*)(ws + 16777216);         // [1024][4096]
    float* bqkv = (float*)(ws + 25165824);       // [3072]
    u16*  xb    = (u16*)(ws + 25178112);         // [8192][1024]  (then reused as att)
    u16*  attb  = xb;
    u16*  qkvb  = (u16*)(ws + 41955328);         // [8192][3072]  (then ao)
    u16*  aob   = qkvb;
    u16*  vtg   = (u16*)(ws + 58732544);         // [64][32][64][64] bf16 (dead before hbb)
    u16*  hbb   = (u16*)(ws + 58732544);         // reused after attention completes
    u16*  ff2b  = (u16*)(ws + 75509760);
    float* hf   = (float*)(ws + 92286976);       // [8192][1024] f32
    u16*  ff1b  = (u16*)(ws + 125841408);        // [8192][4096]
    u16*  kcg   = (u16*)(ws + 125841408);        // [64][2048][64] bf16 (dead before ff1b)

    cast_f32_bf16<<<dim3(4096), dim3(256), 0, stream>>>(x, xb);
    transpose_cast<<<dim3(32, 32), dim3(256), 0, stream>>>(qw, wqkvT, 1024, 1024);
    transpose_cast<<<dim3(32, 32), dim3(256), 0, stream>>>(kw, wqkvT + 1024 * 1024, 1024, 1024);
    transpose_cast<<<dim3(32, 32), dim3(256), 0, stream>>>(vw, wqkvT + 2048 * 1024, 1024, 1024);
    transpose_cast<<<dim3(32, 32), dim3(256), 0, stream>>>(ow, woT, 1024, 1024);
    transpose_cast<<<dim3(128, 32), dim3(256), 0, stream>>>(w1, w1T, 1024, 4096);
    transpose_cast<<<dim3(32, 128), dim3(256), 0, stream>>>(w2, w2T, 4096, 1024);
    concat_bias<<<dim3(12), dim3(256), 0, stream>>>(qb, kb, vb, bqkv);

    // QKV: [8192,1024] x [1024,3072]
    gemm_bf16<<<dim3(24, 64), dim3(256), 0, stream>>>(xb, wqkvT, bqkv, qkvb, 3072, 1024, 0);
    // K/V repack for coalesced attention staging
    transpose_kv<<<dim3(32, 64), dim3(256), 0, stream>>>(qkvb, vtg, kcg);
    // attention (swapped QK^T, in-register softmax)
    attn_flash6<<<dim3(16, 64), dim3(256), 0, stream>>>(qkvb, kcg, vtg, attb);
    // O-proj
    gemm_bf16<<<dim3(8, 64), dim3(256), 0, stream>>>(attb, woT, ob, aob, 1024, 1024, 0);
    // residual + LN1
    ln_fused<<<dim3(2048), dim3(256), 0, stream>>>(x, aob, ln1g, ln1b, hf, hbb);
    // FFN
    gemm_bf16<<<dim3(32, 64), dim3(256), 0, stream>>>(hbb, w1T, b1, ff1b, 4096, 1024, 1);
    gemm_bf16<<<dim3(8, 64), dim3(256), 0, stream>>>(ff1b, w2T, b2, ff2b, 1024, 4096, 0);
    // residual + LN2 -> output (f32)
    ln_fused<<<dim3(2048), dim3(256), 0, stream>>>(hf, ff2b, ln2g, ln2b, (float*)d_out, (u16*)nullptr);
}

// Round 8
// 469.331 us; speedup vs baseline: 1.3547x; 1.0814x over previous
//
#include <hip/hip_runtime.h>
#include <hip/hip_bf16.h>

typedef unsigned short u16;
typedef unsigned int u32;
typedef __attribute__((ext_vector_type(8))) short bf16x8;
typedef __attribute__((ext_vector_type(4))) float f32x4;
typedef __attribute__((ext_vector_type(16))) float f32x16;
typedef __attribute__((ext_vector_type(8))) unsigned short u16x8;
typedef __attribute__((ext_vector_type(4))) unsigned short u16x4;

#define B_ 4
#define S_ 2048
#define E_ 1024
#define H_ 16
#define D_ 64
#define F_ 4096
#define M_ 8192   // B*S tokens

__device__ __forceinline__ float bf2f(u16 u) {
    union { unsigned int i; float f; } v; v.i = ((unsigned int)u) << 16; return v.f;
}
__device__ __forceinline__ u16 f2bf(float f) {
    union { float f; unsigned int i; } v; v.f = f;
    unsigned int r = v.i + 0x7FFFu + ((v.i >> 16) & 1u);
    return (u16)(r >> 16);
}

// ---------------- cast x (f32 -> bf16), 8 elems/thread ----------------
__global__ __launch_bounds__(256) void cast_f32_bf16(const float* __restrict__ in,
                                                     u16* __restrict__ out) {
    const int i = blockIdx.x * 256 + threadIdx.x;
    const f32x4* p = (const f32x4*)in + (size_t)i * 2;
    f32x4 a = p[0], b = p[1];
    u16x8 o;
    o[0] = f2bf(a[0]); o[1] = f2bf(a[1]); o[2] = f2bf(a[2]); o[3] = f2bf(a[3]);
    o[4] = f2bf(b[0]); o[5] = f2bf(b[1]); o[6] = f2bf(b[2]); o[7] = f2bf(b[3]);
    *((u16x8*)out + i) = o;
}

// ---------------- transpose + cast: w[R][C] f32 -> wT[C][R] bf16 ----------------
__global__ __launch_bounds__(256) void transpose_cast(const float* __restrict__ w,
                                                      u16* __restrict__ wT,
                                                      int R, int C) {
    __shared__ float tile[32][33];
    const int tx = threadIdx.x & 31, ty = threadIdx.x >> 5;
    const int c0 = blockIdx.x * 32, r0 = blockIdx.y * 32;
#pragma unroll
    for (int i = 0; i < 4; ++i)
        tile[ty + i * 8][tx] = w[(size_t)(r0 + ty + i * 8) * C + c0 + tx];
    __syncthreads();
#pragma unroll
    for (int i = 0; i < 4; ++i)
        wT[(size_t)(c0 + ty + i * 8) * R + r0 + tx] = f2bf(tile[tx][ty + i * 8]);
}

// ---------------- concat q/k/v bias into [3072] f32 ----------------
__global__ __launch_bounds__(256) void concat_bias(const float* __restrict__ qb,
                                                   const float* __restrict__ kb,
                                                   const float* __restrict__ vb,
                                                   float* __restrict__ dst) {
    const int i = blockIdx.x * 256 + threadIdx.x;
    float v = (i < 1024) ? qb[i] : ((i < 2048) ? kb[i - 1024] : vb[i - 2048]);
    dst[i] = v;
}

// ---------------- K/V repack for attention ----------------
__global__ __launch_bounds__(256) void transpose_kv(const u16* __restrict__ qkv,
                                                    u16* __restrict__ vt,
                                                    u16* __restrict__ kc) {
    __shared__ u16 t2[64 * 66];
    const int s0 = blockIdx.x * 64;
    const int bh = blockIdx.y;
    const int b = bh >> 4, h = bh & 15;
    const size_t ksec = ((size_t)b * S_) * 3072 + 1024 + (size_t)h * 64;
    const size_t vsec = ((size_t)b * S_) * 3072 + 2048 + (size_t)h * 64;
    const int t = threadIdx.x;
    const int sr = t >> 3, dc = (t & 7) * 8;
#pragma unroll
    for (int p = 0; p < 2; ++p) {
        const int s = sr + p * 32;
        u16x8 kv = *(const u16x8*)(qkv + ksec + (size_t)(s0 + s) * 3072 + dc);
        *(u16x8*)(kc + ((size_t)bh * S_ + s0 + s) * 64 + dc) = kv;
        u16x8 v = *(const u16x8*)(qkv + vsec + (size_t)(s0 + s) * 3072 + dc);
#pragma unroll
        for (int e = 0; e < 8; ++e) t2[(dc + e) * 66 + s] = v[e];
    }
    __syncthreads();
    const int dr = t >> 3, sc2 = (t & 7) * 8;
#pragma unroll
    for (int p = 0; p < 2; ++p) {
        const int d = dr + p * 32;
        u16x8 o;
#pragma unroll
        for (int e = 0; e < 8; ++e) o[e] = t2[d * 66 + sc2 + e];
        *(u16x8*)(vt + (((size_t)bh * 32 + blockIdx.x) * 64 + d) * 64 + sc2) = o;
    }
}

// ================= 8-phase 256-tile GEMM (T2+T3+T4+T5) =================
// C[M,N] = A[M,K] * Bt[N,K]^T + bias (+relu). BM=256, BK=64, BN = NR*64.
// 512 threads = 8 waves (2M x 4N). Double-buffered LDS, raw s_barrier (no
// full drains), vmcnt(0) only at K-tile boundaries where the waited loads
// are 2-3 phases old. LDS swizzle: source-pre-swizzled involution
// colb ^= ((row&7)<<4), linear global_load_lds dest, swizzled ds_read (rule 21).
// Buffer-overwrite safety: a buffer is staged only in phases strictly after
// the barrier ending its reads (buf1 read ph4-7 -> staged ph0-1 next iter;
// buf0 read ph0-3 -> staged ph4-5).
#define STAGEA(dst, kt) { \
    _Pragma("unroll") for (int h_ = 0; h_ < 2; ++h_) \
    _Pragma("unroll") for (int j_ = 0; j_ < 2; ++j_) \
        __builtin_amdgcn_global_load_lds( \
            (const __attribute__((address_space(1))) void*)(Ag + (size_t)(h_ * 128 + j_ * 64) * Kb + (size_t)(kt) * 128), \
            (__attribute__((address_space(3))) void*)((char*)(dst) + h_ * 16384 + j_ * 8192 + ldst), 16, 0, 0); }

#define STAGEB(dst, kt) { \
    _Pragma("unroll") for (int h_ = 0; h_ < BN / 128; ++h_) \
    _Pragma("unroll") for (int j_ = 0; j_ < 2; ++j_) \
        __builtin_amdgcn_global_load_lds( \
            (const __attribute__((address_space(1))) void*)(Bg + (size_t)(h_ * 128 + j_ * 64) * Kb + (size_t)(kt) * 128), \
            (__attribute__((address_space(3))) void*)((char*)(dst) + h_ * 16384 + j_ * 8192 + ldst), 16, 0, 0); }

#define LOADA(buf, mg) { \
    _Pragma("unroll") for (int m_ = 0; m_ < 4; ++m_) \
    _Pragma("unroll") for (int kh_ = 0; kh_ < 2; ++kh_) \
        af[m_][kh_] = *(const bf16x8*)((const char*)(buf) + wm * 16384 + ((mg) * 64 + m_ * 16 + lr) * 128 + ((kh_ * 64 + lg * 16) ^ swr)); }

#define LOADB(buf, ng) { \
    _Pragma("unroll") for (int n_ = 0; n_ < NR / 2; ++n_) \
    _Pragma("unroll") for (int kh_ = 0; kh_ < 2; ++kh_) { \
        const int brow_ = wn * (BN / 4) + ((ng) * (NR / 2) + n_) * 16 + lr; \
        bfr[(ng) * (NR / 2) + n_][kh_] = *(const bf16x8*)((const char*)(buf) + (brow_ >> 7) * 16384 + (brow_ & 127) * 128 + ((kh_ * 64 + lg * 16) ^ swr)); } }

#define MFMAQ(mg, ng) { \
    __builtin_amdgcn_s_setprio(1); \
    _Pragma("unroll") for (int m_ = 0; m_ < 4; ++m_) \
    _Pragma("unroll") for (int n_ = 0; n_ < NR / 2; ++n_) \
    _Pragma("unroll") for (int kh_ = 0; kh_ < 2; ++kh_) \
        acc[(mg) * 4 + m_][(ng) * (NR / 2) + n_] = __builtin_amdgcn_mfma_f32_16x16x32_bf16( \
            af[m_][kh_], bfr[(ng) * (NR / 2) + n_][kh_], acc[(mg) * 4 + m_][(ng) * (NR / 2) + n_], 0, 0, 0); \
    __builtin_amdgcn_s_setprio(0); }

#define VMWAIT0 { asm volatile("s_waitcnt vmcnt(0)" ::: "memory"); __builtin_amdgcn_sched_barrier(0); }

template<int NR>
__global__ __launch_bounds__(512, 2) void gemm8p(const u16* __restrict__ A,
                                                 const u16* __restrict__ Bt,
                                                 const float* __restrict__ bias,
                                                 u16* __restrict__ C,
                                                 int N, int K, int relu) {
    constexpr int BN = NR * 64;
    constexpr int ASZ = 16384;       // u16 per 256x64 A tile (32KB)
    constexpr int BSZ = BN * 64;     // u16 per B tile
    __shared__ __align__(16) u16 lds[2 * (ASZ + BSZ)];
    u16* const As0 = lds;
    u16* const Bs0 = lds + ASZ;
    u16* const As1 = lds + ASZ + BSZ;
    u16* const Bs1 = lds + 2 * ASZ + BSZ;

    const int tid = threadIdx.x;
    const int wid = tid >> 6, lane = tid & 63;
    const int wm = wid >> 2, wn = wid & 3;
    const int lr = lane & 15, lg = lane >> 4;
    const int swr = (lr & 7) << 4;
    const int mbase = blockIdx.y * 256, nbase = blockIdx.x * BN;

    // staging source (pre-swizzled), linear LDS dest
    const int r8 = tid >> 3;
    const int swc = ((tid & 7) * 16) ^ ((r8 & 7) << 4);
    const size_t Kb = (size_t)K * 2;
    const char* Ag = (const char*)A + (size_t)(mbase + r8) * Kb + swc;
    const char* Bg = (const char*)Bt + (size_t)(nbase + r8) * Kb + swc;
    const int ldst = tid * 16;

    f32x4 acc[8][NR];
    const f32x4 z = {0.f, 0.f, 0.f, 0.f};
#pragma unroll
    for (int m = 0; m < 8; ++m)
#pragma unroll
        for (int n = 0; n < NR; ++n) acc[m][n] = z;

    bf16x8 af[4][2], bfr[NR][2];

    // prologue: K-tile 0 -> buf0
    STAGEA(As0, 0);
    STAGEB(Bs0, 0);
    VMWAIT0;
    __builtin_amdgcn_s_barrier();

    const int niter = K >> 7;   // 2 K-tiles of 64 per iteration
    for (int i = 0; i < niter; ++i) {
        const int kt1 = 2 * i + 1, kt2 = 2 * i + 2;
        // phase 0: compute buf0 q(0,0); stage kt1 A -> buf1
        LOADA(As0, 0); LOADB(Bs0, 0);
        STAGEA(As1, kt1);
        MFMAQ(0, 0);
        __builtin_amdgcn_s_barrier();
        // phase 1: q(0,1); stage kt1 B -> buf1
        LOADB(Bs0, 1);
        STAGEB(Bs1, kt1);
        MFMAQ(0, 1);
        __builtin_amdgcn_s_barrier();
        // phase 2: q(1,0)
        LOADA(As0, 1);
        MFMAQ(1, 0);
        __builtin_amdgcn_s_barrier();
        // phase 3: q(1,1); boundary: kt1 loads (2-3 phases old) must be in LDS
        MFMAQ(1, 1);
        VMWAIT0;
        __builtin_amdgcn_s_barrier();
        // phase 4: compute buf1 q(0,0); stage kt2 A -> buf0 (buf0 reads ended ph3)
        LOADA(As1, 0); LOADB(Bs1, 0);
        if (i + 1 < niter) STAGEA(As0, kt2);
        MFMAQ(0, 0);
        __builtin_amdgcn_s_barrier();
        // phase 5: q(0,1); stage kt2 B -> buf0
        LOADB(Bs1, 1);
        if (i + 1 < niter) STAGEB(Bs0, kt2);
        MFMAQ(0, 1);
        __builtin_amdgcn_s_barrier();
        // phase 6: q(1,0)
        LOADA(As1, 1);
        MFMAQ(1, 0);
        __builtin_amdgcn_s_barrier();
        // phase 7: q(1,1); boundary for kt2
        MFMAQ(1, 1);
        VMWAIT0;
        __builtin_amdgcn_s_barrier();
    }

    // epilogue: C row = (lane>>4)*4 + reg, col = lane&15 (verified layout)
#pragma unroll
    for (int m = 0; m < 8; ++m) {
        const int row0 = mbase + wm * 128 + m * 16 + lg * 4;
#pragma unroll
        for (int n = 0; n < NR; ++n) {
            const int col = nbase + wn * (BN / 4) + n * 16 + lr;
            const float bz = bias[col];
#pragma unroll
            for (int r = 0; r < 4; ++r) {
                float v = acc[m][n][r] + bz;
                if (relu) v = fmaxf(v, 0.f);
                C[(size_t)(row0 + r) * N + col] = f2bf(v);
            }
        }
    }
}

// ---------------- flash attention v6: swapped QK^T, in-register softmax ----------
__device__ __forceinline__ u32 cvtpk_bf16(float lo, float hi2) {
    u32 r;
    asm("v_cvt_pk_bf16_f32 %0, %1, %2" : "=v"(r) : "v"(lo), "v"(hi2));
    return r;
}
__global__ __launch_bounds__(256) void attn_flash6(const u16* __restrict__ qkv,
                                                   const u16* __restrict__ kcg,
                                                   const u16* __restrict__ vtg,
                                                   u16* __restrict__ att) {
    __shared__ __align__(16) u16 Kt[2][64 * 64];   // 8KB each, swizzled
    __shared__ __align__(16) u16 Vt[2][64 * 64];   // V^T tiles, swizzled
    const int tid = threadIdx.x, wid = tid >> 6;
    const int lane = tid & 63, l31 = lane & 31, hi = lane >> 5;
    const int bh = blockIdx.y, b = bh >> 4, h = bh & 15;
    const size_t tok0 = (size_t)b * S_;
    const int q0 = blockIdx.x * 128 + wid * 32;

    bf16x8 qf[4];
    {
        const u16* qp = qkv + (tok0 + q0 + l31) * 3072 + h * 64 + hi * 8;
#pragma unroll
        for (int dc = 0; dc < 4; ++dc) qf[dc] = *(const bf16x8*)(qp + dc * 16);
    }

    const int srow = tid >> 3;
    const int scolb = ((tid & 7) * 16) ^ ((srow & 7) << 4);
    const u16* kbase = kcg + ((size_t)bh * S_ + srow) * 64 + (scolb >> 1);
    const u16* vbase = vtg + (size_t)bh * 32 * 4096 + srow * 64 + (scolb >> 1);
    const int ldst = tid * 16;

    f32x16 acco0, acco1;
#pragma unroll
    for (int r = 0; r < 16; ++r) { acco0[r] = 0.f; acco1[r] = 0.f; }
    float m_reg = -1e30f, l_run = 0.f;

    __builtin_amdgcn_global_load_lds((const __attribute__((address_space(1))) void*)kbase,
        (__attribute__((address_space(3))) void*)((char*)Kt[0] + ldst), 16, 0, 0);
    __builtin_amdgcn_global_load_lds((const __attribute__((address_space(1))) void*)(kbase + 32 * 64),
        (__attribute__((address_space(3))) void*)((char*)Kt[0] + 4096 + ldst), 16, 0, 0);
    __builtin_amdgcn_global_load_lds((const __attribute__((address_space(1))) void*)vbase,
        (__attribute__((address_space(3))) void*)((char*)Vt[0] + ldst), 16, 0, 0);
    __builtin_amdgcn_global_load_lds((const __attribute__((address_space(1))) void*)(vbase + 32 * 64),
        (__attribute__((address_space(3))) void*)((char*)Vt[0] + 4096 + ldst), 16, 0, 0);
    __syncthreads();

    const float CSC = 0.125f * 1.44269504088896341f;
    const int hb4 = hi * 16;

    for (int kt = 0; kt < 32; ++kt) {
        const int cur = kt & 1;
        if (kt + 1 < 32) {
            const size_t adv = (size_t)(kt + 1) * 4096;
            __builtin_amdgcn_global_load_lds((const __attribute__((address_space(1))) void*)(kbase + adv),
                (__attribute__((address_space(3))) void*)((char*)Kt[cur ^ 1] + ldst), 16, 0, 0);
            __builtin_amdgcn_global_load_lds((const __attribute__((address_space(1))) void*)(kbase + adv + 32 * 64),
                (__attribute__((address_space(3))) void*)((char*)Kt[cur ^ 1] + 4096 + ldst), 16, 0, 0);
            __builtin_amdgcn_global_load_lds((const __attribute__((address_space(1))) void*)(vbase + adv),
                (__attribute__((address_space(3))) void*)((char*)Vt[cur ^ 1] + ldst), 16, 0, 0);
            __builtin_amdgcn_global_load_lds((const __attribute__((address_space(1))) void*)(vbase + adv + 32 * 64),
                (__attribute__((address_space(3))) void*)((char*)Vt[cur ^ 1] + 4096 + ldst), 16, 0, 0);
        }

        f32x16 p0, p1;
#pragma unroll
        for (int r = 0; r < 16; ++r) { p0[r] = 0.f; p1[r] = 0.f; }
        __builtin_amdgcn_s_setprio(1);
#pragma unroll
        for (int dc = 0; dc < 4; ++dc) {
            const int row0 = l31, row1 = 32 + l31;
            const bf16x8 kf0 = *(const bf16x8*)((const char*)Kt[cur] + row0 * 128 + ((dc * 32 + hi * 16) ^ ((row0 & 7) << 4)));
            const bf16x8 kf1 = *(const bf16x8*)((const char*)Kt[cur] + row1 * 128 + ((dc * 32 + hi * 16) ^ ((row1 & 7) << 4)));
            p0 = __builtin_amdgcn_mfma_f32_32x32x16_bf16(kf0, qf[dc], p0, 0, 0, 0);
            p1 = __builtin_amdgcn_mfma_f32_32x32x16_bf16(kf1, qf[dc], p1, 0, 0, 0);
        }
        __builtin_amdgcn_s_setprio(0);

        float mx = p0[0];
#pragma unroll
        for (int r = 1; r < 16; ++r) mx = fmaxf(mx, p0[r]);
#pragma unroll
        for (int r = 0; r < 16; ++r) mx = fmaxf(mx, p1[r]);
        float sa = mx, sb = mx;
        asm volatile("v_permlane32_swap_b32 %0, %1" : "+v"(sa), "+v"(sb));
        const float fullm = fmaxf(sa, sb) * CSC;

        if (!__all(fullm - m_reg <= 8.0f)) {
            const float mnew = fmaxf(m_reg, fullm);
            const float alf = exp2f(m_reg - mnew);
            l_run *= alf;
            m_reg = mnew;
            const int au = __float_as_int(alf);
#pragma unroll
            for (int r = 0; r < 16; ++r) {
                const int addr = ((r & 3) + 8 * (r >> 2)) * 4 + hb4;
                const float ar = __int_as_float(__builtin_amdgcn_ds_bpermute(addr, au));
                acco0[r] *= ar;
                acco1[r] *= ar;
            }
        }

        float pe0[16], pe1[16];
        float ls = 0.f;
#pragma unroll
        for (int r = 0; r < 16; ++r) {
            pe0[r] = exp2f(__builtin_fmaf(p0[r], CSC, -m_reg));
            pe1[r] = exp2f(__builtin_fmaf(p1[r], CSC, -m_reg));
            ls += pe0[r] + pe1[r];
        }
        l_run += ls;

        union { u32 u[4]; bf16x8 v; } pa0, pa1, pa2, pa3;
        {
            u32 a, bswap, c, d;
            a = cvtpk_bf16(pe0[0], pe0[1]);  bswap = cvtpk_bf16(pe0[4], pe0[5]);
            asm volatile("v_permlane32_swap_b32 %0, %1" : "+v"(a), "+v"(bswap));
            c = cvtpk_bf16(pe0[2], pe0[3]);  d = cvtpk_bf16(pe0[6], pe0[7]);
            asm volatile("v_permlane32_swap_b32 %0, %1" : "+v"(c), "+v"(d));
            pa0.u[0] = a; pa0.u[1] = c; pa0.u[2] = bswap; pa0.u[3] = d;
            a = cvtpk_bf16(pe0[8], pe0[9]);  bswap = cvtpk_bf16(pe0[12], pe0[13]);
            asm volatile("v_permlane32_swap_b32 %0, %1" : "+v"(a), "+v"(bswap));
            c = cvtpk_bf16(pe0[10], pe0[11]); d = cvtpk_bf16(pe0[14], pe0[15]);
            asm volatile("v_permlane32_swap_b32 %0, %1" : "+v"(c), "+v"(d));
            pa1.u[0] = a; pa1.u[1] = c; pa1.u[2] = bswap; pa1.u[3] = d;
            a = cvtpk_bf16(pe1[0], pe1[1]);  bswap = cvtpk_bf16(pe1[4], pe1[5]);
            asm volatile("v_permlane32_swap_b32 %0, %1" : "+v"(a), "+v"(bswap));
            c = cvtpk_bf16(pe1[2], pe1[3]);  d = cvtpk_bf16(pe1[6], pe1[7]);
            asm volatile("v_permlane32_swap_b32 %0, %1" : "+v"(c), "+v"(d));
            pa2.u[0] = a; pa2.u[1] = c; pa2.u[2] = bswap; pa2.u[3] = d;
            a = cvtpk_bf16(pe1[8], pe1[9]);  bswap = cvtpk_bf16(pe1[12], pe1[13]);
            asm volatile("v_permlane32_swap_b32 %0, %1" : "+v"(a), "+v"(bswap));
            c = cvtpk_bf16(pe1[10], pe1[11]); d = cvtpk_bf16(pe1[14], pe1[15]);
            asm volatile("v_permlane32_swap_b32 %0, %1" : "+v"(c), "+v"(d));
            pa3.u[0] = a; pa3.u[1] = c; pa3.u[2] = bswap; pa3.u[3] = d;
        }

        __builtin_amdgcn_s_setprio(1);
#pragma unroll
        for (int dblk = 0; dblk < 2; ++dblk) {
            const int row = dblk * 32 + l31;
            const int sw = (row & 7) << 4;
            const char* vrow = (const char*)Vt[cur] + row * 128;
            const bf16x8 v0 = *(const bf16x8*)(vrow + ((0 * 32 + hi * 16) ^ sw));
            const bf16x8 v1 = *(const bf16x8*)(vrow + ((1 * 32 + hi * 16) ^ sw));
            const bf16x8 v2 = *(const bf16x8*)(vrow + ((2 * 32 + hi * 16) ^ sw));
            const bf16x8 v3 = *(const bf16x8*)(vrow + ((3 * 32 + hi * 16) ^ sw));
            if (dblk == 0) {
                acco0 = __builtin_amdgcn_mfma_f32_32x32x16_bf16(pa0.v, v0, acco0, 0, 0, 0);
                acco0 = __builtin_amdgcn_mfma_f32_32x32x16_bf16(pa1.v, v1, acco0, 0, 0, 0);
                acco0 = __builtin_amdgcn_mfma_f32_32x32x16_bf16(pa2.v, v2, acco0, 0, 0, 0);
                acco0 = __builtin_amdgcn_mfma_f32_32x32x16_bf16(pa3.v, v3, acco0, 0, 0, 0);
            } else {
                acco1 = __builtin_amdgcn_mfma_f32_32x32x16_bf16(pa0.v, v0, acco1, 0, 0, 0);
                acco1 = __builtin_amdgcn_mfma_f32_32x32x16_bf16(pa1.v, v1, acco1, 0, 0, 0);
                acco1 = __builtin_amdgcn_mfma_f32_32x32x16_bf16(pa2.v, v2, acco1, 0, 0, 0);
                acco1 = __builtin_amdgcn_mfma_f32_32x32x16_bf16(pa3.v, v3, acco1, 0, 0, 0);
            }
        }
        __builtin_amdgcn_s_setprio(0);

        __syncthreads();
    }

    float la = l_run, lb = l_run;
    asm volatile("v_permlane32_swap_b32 %0, %1" : "+v"(la), "+v"(lb));
    const float linv = 1.0f / (la + lb);
    const int li = __float_as_int(linv);
#pragma unroll
    for (int r = 0; r < 16; ++r) {
        const int addr = ((r & 3) + 8 * (r >> 2)) * 4 + hb4;
        const float lr = __int_as_float(__builtin_amdgcn_ds_bpermute(addr, li));
        const int qrow = (r & 3) + 8 * (r >> 2) + 4 * hi;
        u16* orow = att + (tok0 + q0 + qrow) * E_ + h * 64 + l31;
        orow[0]  = f2bf(acco0[r] * lr);
        orow[32] = f2bf(acco1[r] * lr);
    }
}

// ---------------- fused residual + layernorm ----------------
__global__ __launch_bounds__(256) void ln_fused(const float* __restrict__ xr,
                                                const u16* __restrict__ yb,
                                                const float* __restrict__ g,
                                                const float* __restrict__ bb,
                                                float* __restrict__ ho,
                                                u16* __restrict__ hb) {
    const int wid = threadIdx.x >> 6, lane = threadIdx.x & 63;
    const int row = blockIdx.x * 4 + wid;
    const float* xp = xr + (size_t)row * E_;
    const u16* yp = yb + (size_t)row * E_;

    f32x4 t[4];
    float sum = 0.f, ss = 0.f;
#pragma unroll
    for (int j = 0; j < 4; ++j) {
        const int idx = j * 256 + lane * 4;
        const f32x4 xv = *(const f32x4*)(xp + idx);
        const u16x4 yv = *(const u16x4*)(yp + idx);
        f32x4 tv;
#pragma unroll
        for (int e = 0; e < 4; ++e) tv[e] = xv[e] + bf2f(yv[e]);
        t[j] = tv;
        sum += tv[0] + tv[1] + tv[2] + tv[3];
        ss += tv[0] * tv[0] + tv[1] * tv[1] + tv[2] * tv[2] + tv[3] * tv[3];
    }
#pragma unroll
    for (int off = 1; off < 64; off <<= 1) {
        sum += __shfl_xor(sum, off);
        ss += __shfl_xor(ss, off);
    }
    const float mu = sum * (1.f / 1024.f);
    const float var = ss * (1.f / 1024.f) - mu * mu;
    const float rstd = rsqrtf(var + 1e-5f);
#pragma unroll
    for (int j = 0; j < 4; ++j) {
        const int idx = j * 256 + lane * 4;
        const f32x4 gv = *(const f32x4*)(g + idx);
        const f32x4 bv = *(const f32x4*)(bb + idx);
        f32x4 ov;
#pragma unroll
        for (int e = 0; e < 4; ++e) ov[e] = (t[j][e] - mu) * rstd * gv[e] + bv[e];
        *(f32x4*)(ho + (size_t)row * E_ + idx) = ov;
        if (hb) {
            u16x4 o4;
#pragma unroll
            for (int e = 0; e < 4; ++e) o4[e] = f2bf(ov[e]);
            *(u16x4*)(hb + (size_t)row * E_ + idx) = o4;
        }
    }
}

// ---------------- launch ----------------
extern "C" void kernel_launch(void* const* d_in, const int* in_sizes, int n_in,
                              void* d_out, int out_size, void* d_ws, size_t ws_size,
                              hipStream_t stream) {
    const float* x    = (const float*)d_in[0];
    const float* qw   = (const float*)d_in[1];
    const float* qb   = (const float*)d_in[2];
    const float* kw   = (const float*)d_in[3];
    const float* kb   = (const float*)d_in[4];
    const float* vw   = (const float*)d_in[5];
    const float* vb   = (const float*)d_in[6];
    const float* ow   = (const float*)d_in[7];
    const float* ob   = (const float*)d_in[8];
    const float* ln1g = (const float*)d_in[9];
    const float* ln1b = (const float*)d_in[10];
    const float* w1   = (const float*)d_in[11];
    const float* b1   = (const float*)d_in[12];
    const float* w2   = (const float*)d_in[13];
    const float* b2   = (const float*)d_in[14];
    const float* ln2g = (const float*)d_in[15];
    const float* ln2b = (const float*)d_in[16];

    if (ws_size < 192950272ull) return;

    char* ws = (char*)d_ws;
    u16*  wqkvT = (u16*)(ws + 0);                // [3072][1024] bf16
    u16*  woT   = (u16*)(ws + 6291456);          // [1024][1024]
    u16*  w1T   = (u16*)(ws + 8388608);          // [4096][1024]
    u16*  w2T   = (u16*)(ws + 16777216);         // [1024][4096]
    float* bqkv = (float*)(ws + 25165824);       // [3072]
    u16*  xb    = (u16*)(ws + 25178112);         // [8192][1024]  (then reused as att)
    u16*  attb  = xb;
    u16*  qkvb  = (u16*)(ws + 41955328);         // [8192][3072]  (then ao)
    u16*  aob   = qkvb;
    u16*  vtg   = (u16*)(ws + 58732544);         // [64][32][64][64] bf16 (dead before hbb)
    u16*  hbb   = (u16*)(ws + 58732544);         // reused after attention completes
    u16*  ff2b  = (u16*)(ws + 75509760);
    float* hf   = (float*)(ws + 92286976);       // [8192][1024] f32
    u16*  ff1b  = (u16*)(ws + 125841408);        // [8192][4096]
    u16*  kcg   = (u16*)(ws + 125841408);        // [64][2048][64] bf16 (dead before ff1b)

    cast_f32_bf16<<<dim3(4096), dim3(256), 0, stream>>>(x, xb);
    transpose_cast<<<dim3(32, 32), dim3(256), 0, stream>>>(qw, wqkvT, 1024, 1024);
    transpose_cast<<<dim3(32, 32), dim3(256), 0, stream>>>(kw, wqkvT + 1024 * 1024, 1024, 1024);
    transpose_cast<<<dim3(32, 32), dim3(256), 0, stream>>>(vw, wqkvT + 2048 * 1024, 1024, 1024);
    transpose_cast<<<dim3(32, 32), dim3(256), 0, stream>>>(ow, woT, 1024, 1024);
    transpose_cast<<<dim3(128, 32), dim3(256), 0, stream>>>(w1, w1T, 1024, 4096);
    transpose_cast<<<dim3(32, 128), dim3(256), 0, stream>>>(w2, w2T, 4096, 1024);
    concat_bias<<<dim3(12), dim3(256), 0, stream>>>(qb, kb, vb, bqkv);

    // QKV: [8192,1024] x [1024,3072]
    gemm8p<4><<<dim3(12, 32), dim3(512), 0, stream>>>(xb, wqkvT, bqkv, qkvb, 3072, 1024, 0);
    // K/V repack for coalesced attention staging
    transpose_kv<<<dim3(32, 64), dim3(256), 0, stream>>>(qkvb, vtg, kcg);
    // attention (swapped QK^T, in-register softmax)
    attn_flash6<<<dim3(16, 64), dim3(256), 0, stream>>>(qkvb, kcg, vtg, attb);
    // O-proj: [8192,1024] x [1024,1024]
    gemm8p<2><<<dim3(8, 32), dim3(512), 0, stream>>>(attb, woT, ob, aob, 1024, 1024, 0);
    // residual + LN1
    ln_fused<<<dim3(2048), dim3(256), 0, stream>>>(x, aob, ln1g, ln1b, hf, hbb);
    // FFN
    gemm8p<4><<<dim3(16, 32), dim3(512), 0, stream>>>(hbb, w1T, b1, ff1b, 4096, 1024, 1);
    gemm8p<2><<<dim3(8, 32), dim3(512), 0, stream>>>(ff1b, w2T, b2, ff2b, 1024, 4096, 0);
    // residual + LN2 -> output (f32)
    ln_fused<<<dim3(2048), dim3(256), 0, stream>>>(hf, ff2b, ln2g, ln2b, (float*)d_out, (u16*)nullptr);
}

// Round 9
// 417.850 us; speedup vs baseline: 1.5217x; 1.1232x over previous
//
#include <hip/hip_runtime.h>
#include <hip/hip_bf16.h>

typedef unsigned short u16;
typedef unsigned int u32;
typedef __attribute__((ext_vector_type(8))) short bf16x8;
typedef __attribute__((ext_vector_type(4))) float f32x4;
typedef __attribute__((ext_vector_type(16))) float f32x16;
typedef __attribute__((ext_vector_type(8))) unsigned short u16x8;
typedef __attribute__((ext_vector_type(4))) unsigned short u16x4;

#define B_ 4
#define S_ 2048
#define E_ 1024
#define H_ 16
#define D_ 64
#define F_ 4096
#define M_ 8192   // B*S tokens

__device__ __forceinline__ float bf2f(u16 u) {
    union { unsigned int i; float f; } v; v.i = ((unsigned int)u) << 16; return v.f;
}
__device__ __forceinline__ u16 f2bf(float f) {
    union { float f; unsigned int i; } v; v.f = f;
    unsigned int r = v.i + 0x7FFFu + ((v.i >> 16) & 1u);
    return (u16)(r >> 16);
}

// ---------------- fused prep: x cast + 6 weight transposes + bias concat ----------------
// block ranges: [0,4096) cast x; [4096,5120) qw; [5120,6144) kw; [6144,7168) vw;
// [7168,8192) ow; [8192,12288) w1 (R=1024,C=4096); [12288,16384) w2 (R=4096,C=1024);
// [16384,16396) bias concat.
__global__ __launch_bounds__(256) void prep_all(const float* __restrict__ x, u16* __restrict__ xb,
                                                const float* __restrict__ qw, const float* __restrict__ kw,
                                                const float* __restrict__ vw, const float* __restrict__ ow,
                                                const float* __restrict__ w1, const float* __restrict__ w2,
                                                u16* __restrict__ wqkvT, u16* __restrict__ woT,
                                                u16* __restrict__ w1T, u16* __restrict__ w2T,
                                                const float* __restrict__ qb, const float* __restrict__ kb,
                                                const float* __restrict__ vb, float* __restrict__ bqkv) {
    __shared__ float tile[32][33];
    const int bid = blockIdx.x;
    const int tid = threadIdx.x;
    if (bid < 4096) {
        const int i = bid * 256 + tid;
        const f32x4* p = (const f32x4*)x + (size_t)i * 2;
        f32x4 a = p[0], b = p[1];
        u16x8 o;
        o[0] = f2bf(a[0]); o[1] = f2bf(a[1]); o[2] = f2bf(a[2]); o[3] = f2bf(a[3]);
        o[4] = f2bf(b[0]); o[5] = f2bf(b[1]); o[6] = f2bf(b[2]); o[7] = f2bf(b[3]);
        *((u16x8*)xb + i) = o;
        return;
    }
    if (bid >= 16384) {
        const int i = (bid - 16384) * 256 + tid;
        float v = (i < 1024) ? qb[i] : ((i < 2048) ? kb[i - 1024] : vb[i - 2048]);
        bqkv[i] = v;
        return;
    }
    // transpose tasks
    const float* src; u16* dst; int R, C, bx, by;
    if (bid < 8192) {              // 1024x1024 squares
        const int t = (bid - 4096) >> 10, lb = (bid - 4096) & 1023;
        R = 1024; C = 1024;
        bx = lb & 31; by = lb >> 5;
        if (t == 0)      { src = qw; dst = wqkvT; }
        else if (t == 1) { src = kw; dst = wqkvT + 1024 * 1024; }
        else if (t == 2) { src = vw; dst = wqkvT + 2048 * 1024; }
        else             { src = ow; dst = woT; }
    } else if (bid < 12288) {      // w1: R=1024, C=4096
        const int lb = bid - 8192;
        R = 1024; C = 4096;
        bx = lb & 127; by = lb >> 7;
        src = w1; dst = w1T;
    } else {                        // w2: R=4096, C=1024
        const int lb = bid - 12288;
        R = 4096; C = 1024;
        bx = lb & 31; by = lb >> 5;
        src = w2; dst = w2T;
    }
    const int tx = tid & 31, ty = tid >> 5;
    const int c0 = bx * 32, r0 = by * 32;
#pragma unroll
    for (int i = 0; i < 4; ++i)
        tile[ty + i * 8][tx] = src[(size_t)(r0 + ty + i * 8) * C + c0 + tx];
    __syncthreads();
#pragma unroll
    for (int i = 0; i < 4; ++i)
        dst[(size_t)(c0 + ty + i * 8) * R + r0 + tx] = f2bf(tile[tx][ty + i * 8]);
}

// ---------------- V repack: qkv V-section -> vt[bh][kt:32][d:64][k:64] ----------------
__global__ __launch_bounds__(256) void transpose_v(const u16* __restrict__ qkv,
                                                   u16* __restrict__ vt) {
    __shared__ u16 t2[64 * 66];
    const int s0 = blockIdx.x * 64;
    const int bh = blockIdx.y;
    const int b = bh >> 4, h = bh & 15;
    const size_t vsec = ((size_t)b * S_) * 3072 + 2048 + (size_t)h * 64;
    const int t = threadIdx.x;
    const int sr = t >> 3, dc = (t & 7) * 8;
#pragma unroll
    for (int p = 0; p < 2; ++p) {
        const int s = sr + p * 32;
        u16x8 v = *(const u16x8*)(qkv + vsec + (size_t)(s0 + s) * 3072 + dc);
#pragma unroll
        for (int e = 0; e < 8; ++e) t2[(dc + e) * 66 + s] = v[e];
    }
    __syncthreads();
    const int dr = t >> 3, sc2 = (t & 7) * 8;
#pragma unroll
    for (int p = 0; p < 2; ++p) {
        const int d = dr + p * 32;
        u16x8 o;
#pragma unroll
        for (int e = 0; e < 8; ++e) o[e] = t2[d * 66 + sc2 + e];
        *(u16x8*)(vt + (((size_t)bh * 32 + blockIdx.x) * 64 + d) * 64 + sc2) = o;
    }
}

// ================= 8-phase 256-tile GEMM (T1+T2+T3+T4+T5) =================
#define STAGEA(dst, kt) { \
    _Pragma("unroll") for (int h_ = 0; h_ < 2; ++h_) \
    _Pragma("unroll") for (int j_ = 0; j_ < 2; ++j_) \
        __builtin_amdgcn_global_load_lds( \
            (const __attribute__((address_space(1))) void*)(Ag + (size_t)(h_ * 128 + j_ * 64) * Kb + (size_t)(kt) * 128), \
            (__attribute__((address_space(3))) void*)((char*)(dst) + h_ * 16384 + j_ * 8192 + ldst), 16, 0, 0); }

#define STAGEB(dst, kt) { \
    _Pragma("unroll") for (int h_ = 0; h_ < BN / 128; ++h_) \
    _Pragma("unroll") for (int j_ = 0; j_ < 2; ++j_) \
        __builtin_amdgcn_global_load_lds( \
            (const __attribute__((address_space(1))) void*)(Bg + (size_t)(h_ * 128 + j_ * 64) * Kb + (size_t)(kt) * 128), \
            (__attribute__((address_space(3))) void*)((char*)(dst) + h_ * 16384 + j_ * 8192 + ldst), 16, 0, 0); }

#define LOADA(buf, mg) { \
    _Pragma("unroll") for (int m_ = 0; m_ < 4; ++m_) \
    _Pragma("unroll") for (int kh_ = 0; kh_ < 2; ++kh_) \
        af[m_][kh_] = *(const bf16x8*)((const char*)(buf) + wm * 16384 + ((mg) * 64 + m_ * 16 + lr) * 128 + ((kh_ * 64 + lg * 16) ^ swr)); }

#define LOADB(buf, ng) { \
    _Pragma("unroll") for (int n_ = 0; n_ < NR / 2; ++n_) \
    _Pragma("unroll") for (int kh_ = 0; kh_ < 2; ++kh_) { \
        const int brow_ = wn * (BN / 4) + ((ng) * (NR / 2) + n_) * 16 + lr; \
        bfr[(ng) * (NR / 2) + n_][kh_] = *(const bf16x8*)((const char*)(buf) + (brow_ >> 7) * 16384 + (brow_ & 127) * 128 + ((kh_ * 64 + lg * 16) ^ swr)); } }

#define MFMAQ(mg, ng) { \
    __builtin_amdgcn_s_setprio(1); \
    _Pragma("unroll") for (int m_ = 0; m_ < 4; ++m_) \
    _Pragma("unroll") for (int n_ = 0; n_ < NR / 2; ++n_) \
    _Pragma("unroll") for (int kh_ = 0; kh_ < 2; ++kh_) \
        acc[(mg) * 4 + m_][(ng) * (NR / 2) + n_] = __builtin_amdgcn_mfma_f32_16x16x32_bf16( \
            af[m_][kh_], bfr[(ng) * (NR / 2) + n_][kh_], acc[(mg) * 4 + m_][(ng) * (NR / 2) + n_], 0, 0, 0); \
    __builtin_amdgcn_s_setprio(0); }

#define VMWAIT0 { asm volatile("s_waitcnt vmcnt(0)" ::: "memory"); __builtin_amdgcn_sched_barrier(0); }

template<int NR>
__global__ __launch_bounds__(512, 2) void gemm8p(const u16* __restrict__ A,
                                                 const u16* __restrict__ Bt,
                                                 const float* __restrict__ bias,
                                                 u16* __restrict__ C,
                                                 int N, int K, int relu) {
    constexpr int BN = NR * 64;
    constexpr int ASZ = 16384;
    constexpr int BSZ = BN * 64;
    __shared__ __align__(16) u16 lds[2 * (ASZ + BSZ)];
    u16* const As0 = lds;
    u16* const Bs0 = lds + ASZ;
    u16* const As1 = lds + ASZ + BSZ;
    u16* const Bs1 = lds + 2 * ASZ + BSZ;

    const int tid = threadIdx.x;
    const int wid = tid >> 6, lane = tid & 63;
    const int wm = wid >> 2, wn = wid & 3;
    const int lr = lane & 15, lg = lane >> 4;
    const int swr = (lr & 7) << 4;

    // XCD-chunked swizzle (all grids are multiples of 8)
    int lin = blockIdx.y * gridDim.x + blockIdx.x;
    const int nwg = gridDim.x * gridDim.y;
    const int cpx = nwg >> 3;
    lin = (lin & 7) * cpx + (lin >> 3);
    const int bxn = lin % gridDim.x, byn = lin / gridDim.x;
    const int mbase = byn * 256, nbase = bxn * BN;

    const int r8 = tid >> 3;
    const int swc = ((tid & 7) * 16) ^ ((r8 & 7) << 4);
    const size_t Kb = (size_t)K * 2;
    const char* Ag = (const char*)A + (size_t)(mbase + r8) * Kb + swc;
    const char* Bg = (const char*)Bt + (size_t)(nbase + r8) * Kb + swc;
    const int ldst = tid * 16;

    f32x4 acc[8][NR];
    const f32x4 z = {0.f, 0.f, 0.f, 0.f};
#pragma unroll
    for (int m = 0; m < 8; ++m)
#pragma unroll
        for (int n = 0; n < NR; ++n) acc[m][n] = z;

    bf16x8 af[4][2], bfr[NR][2];

    STAGEA(As0, 0);
    STAGEB(Bs0, 0);
    VMWAIT0;
    __builtin_amdgcn_s_barrier();

    const int niter = K >> 7;
    for (int i = 0; i < niter; ++i) {
        const int kt1 = 2 * i + 1, kt2 = 2 * i + 2;
        LOADA(As0, 0); LOADB(Bs0, 0);
        STAGEA(As1, kt1);
        MFMAQ(0, 0);
        __builtin_amdgcn_s_barrier();
        LOADB(Bs0, 1);
        STAGEB(Bs1, kt1);
        MFMAQ(0, 1);
        __builtin_amdgcn_s_barrier();
        LOADA(As0, 1);
        MFMAQ(1, 0);
        __builtin_amdgcn_s_barrier();
        MFMAQ(1, 1);
        VMWAIT0;
        __builtin_amdgcn_s_barrier();
        LOADA(As1, 0); LOADB(Bs1, 0);
        if (i + 1 < niter) STAGEA(As0, kt2);
        MFMAQ(0, 0);
        __builtin_amdgcn_s_barrier();
        LOADB(Bs1, 1);
        if (i + 1 < niter) STAGEB(Bs0, kt2);
        MFMAQ(0, 1);
        __builtin_amdgcn_s_barrier();
        LOADA(As1, 1);
        MFMAQ(1, 0);
        __builtin_amdgcn_s_barrier();
        MFMAQ(1, 1);
        VMWAIT0;
        __builtin_amdgcn_s_barrier();
    }

#pragma unroll
    for (int m = 0; m < 8; ++m) {
        const int row0 = mbase + wm * 128 + m * 16 + lg * 4;
#pragma unroll
        for (int n = 0; n < NR; ++n) {
            const int col = nbase + wn * (BN / 4) + n * 16 + lr;
            const float bz = bias[col];
#pragma unroll
            for (int r = 0; r < 4; ++r) {
                float v = acc[m][n][r] + bz;
                if (relu) v = fmaxf(v, 0.f);
                C[(size_t)(row0 + r) * N + col] = f2bf(v);
            }
        }
    }
}

// ---------------- flash attention v7: swapped QK^T, in-register softmax, ones-l ----------
__device__ __forceinline__ u32 cvtpk_bf16(float lo, float hi2) {
    u32 r;
    asm("v_cvt_pk_bf16_f32 %0, %1, %2" : "=v"(r) : "v"(lo), "v"(hi2));
    return r;
}
__global__ __launch_bounds__(256) void attn_flash7(const u16* __restrict__ qkv,
                                                   const u16* __restrict__ vtg,
                                                   u16* __restrict__ att) {
    __shared__ __align__(16) u16 Kt[2][64 * 64];
    __shared__ __align__(16) u16 Vt[2][64 * 64];
    const int tid = threadIdx.x, wid = tid >> 6;
    const int lane = tid & 63, l31 = lane & 31, hi = lane >> 5;
    // XCD-chunked swizzle: all q-tiles of one bh on one XCD (K/V 512KB x 8 bh = one L2)
    int lin = blockIdx.y * 16 + blockIdx.x;
    lin = (lin & 7) * 128 + (lin >> 3);
    const int bh = lin >> 4, qt = lin & 15;
    const int b = bh >> 4, h = bh & 15;
    const size_t tok0 = (size_t)b * S_;
    const int q0 = qt * 128 + wid * 32;

    bf16x8 qf[4];
    {
        const u16* qp = qkv + (tok0 + q0 + l31) * 3072 + h * 64 + hi * 8;
#pragma unroll
        for (int dc = 0; dc < 4; ++dc) qf[dc] = *(const bf16x8*)(qp + dc * 16);
    }

    // staging sources (pre-swizzled involution; linear LDS dest) — K direct from qkv
    const int srow = tid >> 3;
    const int scolb = ((tid & 7) * 16) ^ ((srow & 7) << 4);
    const u16* kbase = qkv + (tok0 + srow) * 3072 + 1024 + h * 64 + (scolb >> 1);
    const u16* vbase = vtg + (size_t)bh * 32 * 4096 + srow * 64 + (scolb >> 1);
    const int ldst = tid * 16;

    f32x16 acco0, acco1, lacc;
#pragma unroll
    for (int r = 0; r < 16; ++r) { acco0[r] = 0.f; acco1[r] = 0.f; lacc[r] = 0.f; }
    float m_reg = -1e30f;
    const f32x16 z16 = {0.f,0.f,0.f,0.f,0.f,0.f,0.f,0.f,0.f,0.f,0.f,0.f,0.f,0.f,0.f,0.f};
    const short oneb = (short)0x3F80;
    const bf16x8 onesv = {oneb, oneb, oneb, oneb, oneb, oneb, oneb, oneb};

    __builtin_amdgcn_global_load_lds((const __attribute__((address_space(1))) void*)kbase,
        (__attribute__((address_space(3))) void*)((char*)Kt[0] + ldst), 16, 0, 0);
    __builtin_amdgcn_global_load_lds((const __attribute__((address_space(1))) void*)(kbase + 32 * 3072),
        (__attribute__((address_space(3))) void*)((char*)Kt[0] + 4096 + ldst), 16, 0, 0);
    __builtin_amdgcn_global_load_lds((const __attribute__((address_space(1))) void*)vbase,
        (__attribute__((address_space(3))) void*)((char*)Vt[0] + ldst), 16, 0, 0);
    __builtin_amdgcn_global_load_lds((const __attribute__((address_space(1))) void*)(vbase + 32 * 64),
        (__attribute__((address_space(3))) void*)((char*)Vt[0] + 4096 + ldst), 16, 0, 0);
    __syncthreads();

    const float CSC = 0.125f * 1.44269504088896341f;
    const int hb4 = hi * 16;

    for (int kt = 0; kt < 32; ++kt) {
        const int cur = kt & 1;
        if (kt + 1 < 32) {
            const size_t advk = (size_t)(kt + 1) * 64 * 3072;
            const size_t advv = (size_t)(kt + 1) * 4096;
            __builtin_amdgcn_global_load_lds((const __attribute__((address_space(1))) void*)(kbase + advk),
                (__attribute__((address_space(3))) void*)((char*)Kt[cur ^ 1] + ldst), 16, 0, 0);
            __builtin_amdgcn_global_load_lds((const __attribute__((address_space(1))) void*)(kbase + advk + 32 * 3072),
                (__attribute__((address_space(3))) void*)((char*)Kt[cur ^ 1] + 4096 + ldst), 16, 0, 0);
            __builtin_amdgcn_global_load_lds((const __attribute__((address_space(1))) void*)(vbase + advv),
                (__attribute__((address_space(3))) void*)((char*)Vt[cur ^ 1] + ldst), 16, 0, 0);
            __builtin_amdgcn_global_load_lds((const __attribute__((address_space(1))) void*)(vbase + advv + 32 * 64),
                (__attribute__((address_space(3))) void*)((char*)Vt[cur ^ 1] + 4096 + ldst), 16, 0, 0);
        }

        // swapped QK^T (first MFMA consumes the zero vector: no per-iter init)
        f32x16 p0, p1;
        __builtin_amdgcn_s_setprio(1);
#pragma unroll
        for (int dc = 0; dc < 4; ++dc) {
            const int row0 = l31, row1 = 32 + l31;
            const bf16x8 kf0 = *(const bf16x8*)((const char*)Kt[cur] + row0 * 128 + ((dc * 32 + hi * 16) ^ ((row0 & 7) << 4)));
            const bf16x8 kf1 = *(const bf16x8*)((const char*)Kt[cur] + row1 * 128 + ((dc * 32 + hi * 16) ^ ((row1 & 7) << 4)));
            p0 = __builtin_amdgcn_mfma_f32_32x32x16_bf16(kf0, qf[dc], dc == 0 ? z16 : p0, 0, 0, 0);
            p1 = __builtin_amdgcn_mfma_f32_32x32x16_bf16(kf1, qf[dc], dc == 0 ? z16 : p1, 0, 0, 0);
        }
        __builtin_amdgcn_s_setprio(0);

        // row max: max3-fusable triples
        float mx = fmaxf(p0[0], p0[1]);
#pragma unroll
        for (int r = 2; r < 16; r += 2) mx = fmaxf(fmaxf(mx, p0[r]), p0[r + 1]);
#pragma unroll
        for (int r = 0; r < 16; r += 2) mx = fmaxf(fmaxf(mx, p1[r]), p1[r + 1]);
        float sa = mx, sb = mx;
        asm volatile("v_permlane32_swap_b32 %0, %1" : "+v"(sa), "+v"(sb));
        const float fullm = fmaxf(sa, sb) * CSC;

        // defer-max: rescale only on significant growth
        if (!__all(fullm - m_reg <= 8.0f)) {
            const float mnew = fmaxf(m_reg, fullm);
            const float alf = exp2f(m_reg - mnew);
            m_reg = mnew;
            const int au = __float_as_int(alf);
#pragma unroll
            for (int r = 0; r < 16; ++r) {
                const int addr = ((r & 3) + 8 * (r >> 2)) * 4 + hb4;
                const float ar = __int_as_float(__builtin_amdgcn_ds_bpermute(addr, au));
                acco0[r] *= ar;
                acco1[r] *= ar;
                lacc[r] *= ar;
            }
        }

        float pe0[16], pe1[16];
#pragma unroll
        for (int r = 0; r < 16; ++r) {
            pe0[r] = exp2f(__builtin_fmaf(p0[r], CSC, -m_reg));
            pe1[r] = exp2f(__builtin_fmaf(p1[r], CSC, -m_reg));
        }

        union { u32 u[4]; bf16x8 v; } pa0, pa1, pa2, pa3;
        {
            u32 a, bswap, c, d;
            a = cvtpk_bf16(pe0[0], pe0[1]);  bswap = cvtpk_bf16(pe0[4], pe0[5]);
            asm volatile("v_permlane32_swap_b32 %0, %1" : "+v"(a), "+v"(bswap));
            c = cvtpk_bf16(pe0[2], pe0[3]);  d = cvtpk_bf16(pe0[6], pe0[7]);
            asm volatile("v_permlane32_swap_b32 %0, %1" : "+v"(c), "+v"(d));
            pa0.u[0] = a; pa0.u[1] = c; pa0.u[2] = bswap; pa0.u[3] = d;
            a = cvtpk_bf16(pe0[8], pe0[9]);  bswap = cvtpk_bf16(pe0[12], pe0[13]);
            asm volatile("v_permlane32_swap_b32 %0, %1" : "+v"(a), "+v"(bswap));
            c = cvtpk_bf16(pe0[10], pe0[11]); d = cvtpk_bf16(pe0[14], pe0[15]);
            asm volatile("v_permlane32_swap_b32 %0, %1" : "+v"(c), "+v"(d));
            pa1.u[0] = a; pa1.u[1] = c; pa1.u[2] = bswap; pa1.u[3] = d;
            a = cvtpk_bf16(pe1[0], pe1[1]);  bswap = cvtpk_bf16(pe1[4], pe1[5]);
            asm volatile("v_permlane32_swap_b32 %0, %1" : "+v"(a), "+v"(bswap));
            c = cvtpk_bf16(pe1[2], pe1[3]);  d = cvtpk_bf16(pe1[6], pe1[7]);
            asm volatile("v_permlane32_swap_b32 %0, %1" : "+v"(c), "+v"(d));
            pa2.u[0] = a; pa2.u[1] = c; pa2.u[2] = bswap; pa2.u[3] = d;
            a = cvtpk_bf16(pe1[8], pe1[9]);  bswap = cvtpk_bf16(pe1[12], pe1[13]);
            asm volatile("v_permlane32_swap_b32 %0, %1" : "+v"(a), "+v"(bswap));
            c = cvtpk_bf16(pe1[10], pe1[11]); d = cvtpk_bf16(pe1[14], pe1[15]);
            asm volatile("v_permlane32_swap_b32 %0, %1" : "+v"(c), "+v"(d));
            pa3.u[0] = a; pa3.u[1] = c; pa3.u[2] = bswap; pa3.u[3] = d;
        }

        __builtin_amdgcn_s_setprio(1);
        // l row-sums via ones-column MFMAs (replaces VALU adds; bf16-consistent with PV)
        lacc = __builtin_amdgcn_mfma_f32_32x32x16_bf16(pa0.v, onesv, lacc, 0, 0, 0);
        lacc = __builtin_amdgcn_mfma_f32_32x32x16_bf16(pa1.v, onesv, lacc, 0, 0, 0);
        lacc = __builtin_amdgcn_mfma_f32_32x32x16_bf16(pa2.v, onesv, lacc, 0, 0, 0);
        lacc = __builtin_amdgcn_mfma_f32_32x32x16_bf16(pa3.v, onesv, lacc, 0, 0, 0);
#pragma unroll
        for (int dblk = 0; dblk < 2; ++dblk) {
            const int row = dblk * 32 + l31;
            const int sw = (row & 7) << 4;
            const char* vrow = (const char*)Vt[cur] + row * 128;
            const bf16x8 v0 = *(const bf16x8*)(vrow + ((0 * 32 + hi * 16) ^ sw));
            const bf16x8 v1 = *(const bf16x8*)(vrow + ((1 * 32 + hi * 16) ^ sw));
            const bf16x8 v2 = *(const bf16x8*)(vrow + ((2 * 32 + hi * 16) ^ sw));
            const bf16x8 v3 = *(const bf16x8*)(vrow + ((3 * 32 + hi * 16) ^ sw));
            if (dblk == 0) {
                acco0 = __builtin_amdgcn_mfma_f32_32x32x16_bf16(pa0.v, v0, acco0, 0, 0, 0);
                acco0 = __builtin_amdgcn_mfma_f32_32x32x16_bf16(pa1.v, v1, acco0, 0, 0, 0);
                acco0 = __builtin_amdgcn_mfma_f32_32x32x16_bf16(pa2.v, v2, acco0, 0, 0, 0);
                acco0 = __builtin_amdgcn_mfma_f32_32x32x16_bf16(pa3.v, v3, acco0, 0, 0, 0);
            } else {
                acco1 = __builtin_amdgcn_mfma_f32_32x32x16_bf16(pa0.v, v0, acco1, 0, 0, 0);
                acco1 = __builtin_amdgcn_mfma_f32_32x32x16_bf16(pa1.v, v1, acco1, 0, 0, 0);
                acco1 = __builtin_amdgcn_mfma_f32_32x32x16_bf16(pa2.v, v2, acco1, 0, 0, 0);
                acco1 = __builtin_amdgcn_mfma_f32_32x32x16_bf16(pa3.v, v3, acco1, 0, 0, 0);
            }
        }
        __builtin_amdgcn_s_setprio(0);

        __syncthreads();
    }

    // epilogue: lacc[r] is the full row-sum (both lane halves, all keys) — no cross-lane ops
#pragma unroll
    for (int r = 0; r < 16; ++r) {
        const float lr = 1.0f / lacc[r];
        const int qrow = (r & 3) + 8 * (r >> 2) + 4 * hi;
        u16* orow = att + (tok0 + q0 + qrow) * E_ + h * 64 + l31;
        orow[0]  = f2bf(acco0[r] * lr);
        orow[32] = f2bf(acco1[r] * lr);
    }
}

// ---------------- fused residual + layernorm ----------------
__global__ __launch_bounds__(256) void ln_fused(const float* __restrict__ xr,
                                                const u16* __restrict__ yb,
                                                const float* __restrict__ g,
                                                const float* __restrict__ bb,
                                                float* __restrict__ ho,
                                                u16* __restrict__ hb) {
    const int wid = threadIdx.x >> 6, lane = threadIdx.x & 63;
    const int row = blockIdx.x * 4 + wid;
    const float* xp = xr + (size_t)row * E_;
    const u16* yp = yb + (size_t)row * E_;

    f32x4 t[4];
    float sum = 0.f, ss = 0.f;
#pragma unroll
    for (int j = 0; j < 4; ++j) {
        const int idx = j * 256 + lane * 4;
        const f32x4 xv = *(const f32x4*)(xp + idx);
        const u16x4 yv = *(const u16x4*)(yp + idx);
        f32x4 tv;
#pragma unroll
        for (int e = 0; e < 4; ++e) tv[e] = xv[e] + bf2f(yv[e]);
        t[j] = tv;
        sum += tv[0] + tv[1] + tv[2] + tv[3];
        ss += tv[0] * tv[0] + tv[1] * tv[1] + tv[2] * tv[2] + tv[3] * tv[3];
    }
#pragma unroll
    for (int off = 1; off < 64; off <<= 1) {
        sum += __shfl_xor(sum, off);
        ss += __shfl_xor(ss, off);
    }
    const float mu = sum * (1.f / 1024.f);
    const float var = ss * (1.f / 1024.f) - mu * mu;
    const float rstd = rsqrtf(var + 1e-5f);
#pragma unroll
    for (int j = 0; j < 4; ++j) {
        const int idx = j * 256 + lane * 4;
        const f32x4 gv = *(const f32x4*)(g + idx);
        const f32x4 bv = *(const f32x4*)(bb + idx);
        f32x4 ov;
#pragma unroll
        for (int e = 0; e < 4; ++e) ov[e] = (t[j][e] - mu) * rstd * gv[e] + bv[e];
        *(f32x4*)(ho + (size_t)row * E_ + idx) = ov;
        if (hb) {
            u16x4 o4;
#pragma unroll
            for (int e = 0; e < 4; ++e) o4[e] = f2bf(ov[e]);
            *(u16x4*)(hb + (size_t)row * E_ + idx) = o4;
        }
    }
}

// ---------------- launch ----------------
extern "C" void kernel_launch(void* const* d_in, const int* in_sizes, int n_in,
                              void* d_out, int out_size, void* d_ws, size_t ws_size,
                              hipStream_t stream) {
    const float* x    = (const float*)d_in[0];
    const float* qw   = (const float*)d_in[1];
    const float* qb   = (const float*)d_in[2];
    const float* kw   = (const float*)d_in[3];
    const float* kb   = (const float*)d_in[4];
    const float* vw   = (const float*)d_in[5];
    const float* vb   = (const float*)d_in[6];
    const float* ow   = (const float*)d_in[7];
    const float* ob   = (const float*)d_in[8];
    const float* ln1g = (const float*)d_in[9];
    const float* ln1b = (const float*)d_in[10];
    const float* w1   = (const float*)d_in[11];
    const float* b1   = (const float*)d_in[12];
    const float* w2   = (const float*)d_in[13];
    const float* b2   = (const float*)d_in[14];
    const float* ln2g = (const float*)d_in[15];
    const float* ln2b = (const float*)d_in[16];

    if (ws_size < 192950272ull) return;

    char* ws = (char*)d_ws;
    u16*  wqkvT = (u16*)(ws + 0);                // [3072][1024] bf16
    u16*  woT   = (u16*)(ws + 6291456);          // [1024][1024]
    u16*  w1T   = (u16*)(ws + 8388608);          // [4096][1024]
    u16*  w2T   = (u16*)(ws + 16777216);         // [1024][4096]
    float* bqkv = (float*)(ws + 25165824);       // [3072]
    u16*  xb    = (u16*)(ws + 25178112);         // [8192][1024]  (then reused as att)
    u16*  attb  = xb;
    u16*  qkvb  = (u16*)(ws + 41955328);         // [8192][3072]  (then ao)
    u16*  aob   = qkvb;
    u16*  vtg   = (u16*)(ws + 58732544);         // [64][32][64][64] bf16 (dead before hbb)
    u16*  hbb   = (u16*)(ws + 58732544);         // reused after attention completes
    u16*  ff2b  = (u16*)(ws + 75509760);
    float* hf   = (float*)(ws + 92286976);       // [8192][1024] f32
    u16*  ff1b  = (u16*)(ws + 125841408);        // [8192][4096]

    // fused prep (1 launch)
    prep_all<<<dim3(16396), dim3(256), 0, stream>>>(x, xb, qw, kw, vw, ow, w1, w2,
                                                    wqkvT, woT, w1T, w2T, qb, kb, vb, bqkv);
    // QKV: [8192,1024] x [1024,3072]
    gemm8p<4><<<dim3(12, 32), dim3(512), 0, stream>>>(xb, wqkvT, bqkv, qkvb, 3072, 1024, 0);
    // V repack
    transpose_v<<<dim3(32, 64), dim3(256), 0, stream>>>(qkvb, vtg);
    // attention
    attn_flash7<<<dim3(16, 64), dim3(256), 0, stream>>>(qkvb, vtg, attb);
    // O-proj
    gemm8p<2><<<dim3(8, 32), dim3(512), 0, stream>>>(attb, woT, ob, aob, 1024, 1024, 0);
    // residual + LN1
    ln_fused<<<dim3(2048), dim3(256), 0, stream>>>(x, aob, ln1g, ln1b, hf, hbb);
    // FFN
    gemm8p<4><<<dim3(16, 32), dim3(512), 0, stream>>>(hbb, w1T, b1, ff1b, 4096, 1024, 1);
    gemm8p<2><<<dim3(8, 32), dim3(512), 0, stream>>>(ff1b, w2T, b2, ff2b, 1024, 4096, 0);
    // residual + LN2 -> output (f32)
    ln_fused<<<dim3(2048), dim3(256), 0, stream>>>(hf, ff2b, ln2g, ln2b, (float*)d_out, (u16*)nullptr);
}